// Round 1
// baseline (320.557 us; speedup 1.0000x reference)
//
#include <hip/hip_runtime.h>
#include <math.h>

#define B_SZ 512
#define LG 48
#define T_LEN 128
#define DIM 300
#define NA 2048
#define NC 2048
#define NH 4
#define DK 75
#define KTOP 96
#define RPB 16

// ---------------------------------------------------------------------------
// Kernel 1: aspect embedding  aa_embed[n] = sum_t mask[n,t] * embed[map_AA[n],t,:]
// writes compact X row n, registers slot_src.
// ---------------------------------------------------------------------------
__global__ __launch_bounds__(256) void aspect_kernel(
    const float* __restrict__ embed, const float* __restrict__ mask,
    const int* __restrict__ mapAA, const int* __restrict__ mapAAi,
    float* __restrict__ X, int* __restrict__ slot_src) {
  int n = blockIdx.x;
  __shared__ float m[T_LEN];
  if (threadIdx.x < T_LEN) m[threadIdx.x] = mask[n * T_LEN + threadIdx.x];
  __syncthreads();
  const float* src = embed + (size_t)mapAA[n] * T_LEN * DIM;
  int d0 = threadIdx.x;        // < 256 < 300, always valid
  int d1 = threadIdx.x + 256;  // valid if < 300
  float a0 = 0.f, a1 = 0.f;
  for (int t = 0; t < T_LEN; ++t) {
    float mv = m[t];
    const float* row = src + t * DIM;
    a0 += mv * row[d0];
    if (d1 < DIM) a1 += mv * row[d1];
  }
  X[(size_t)n * DIM + d0] = a0;
  if (d1 < DIM) X[(size_t)n * DIM + d1] = a1;
  if (threadIdx.x == 0) slot_src[mapAA[n] * LG + mapAAi[n]] = n;
}

// ---------------------------------------------------------------------------
// Kernel 2: clause rows -> X[NA+n], slot_src, out_idx (runs AFTER aspect_kernel
// so collisions resolve like the reference's second .set)
// ---------------------------------------------------------------------------
__global__ __launch_bounds__(256) void clause_kernel(
    const float* __restrict__ clause,
    const int* __restrict__ mapAS, const int* __restrict__ mapASi,
    float* __restrict__ X, int* __restrict__ slot_src, int* __restrict__ out_idx) {
  int n = blockIdx.x;
  for (int d = threadIdx.x; d < DIM; d += 256)
    X[(size_t)(NA + n) * DIM + d] = clause[(size_t)n * DIM + d];
  if (threadIdx.x == 0) {
    int s = mapAS[n] * LG + mapASi[n];
    slot_src[s] = NA + n;
    out_idx[s] = n;
  }
}

// ---------------------------------------------------------------------------
// Kernel 3: QK projection over compact rows: QK[r, 0:300]=q, [300:600]=k
// 16 rows per block staged in LDS, 3 columns per thread in registers.
// ---------------------------------------------------------------------------
__global__ __launch_bounds__(256) void qk_kernel(
    const float* __restrict__ X, const float* __restrict__ Wq,
    const float* __restrict__ bq, const float* __restrict__ Wk,
    const float* __restrict__ bk, float* __restrict__ QK) {
  int r0 = blockIdx.x * RPB;
  __shared__ float xs[RPB][DIM];
  for (int i = threadIdx.x; i < RPB * DIM; i += 256) {
    int r = i / DIM;
    xs[r][i - r * DIM] = X[(size_t)r0 * DIM + i];
  }
  __syncthreads();
  int c0 = threadIdx.x;          // 0..255   -> Wq
  int c1 = threadIdx.x + 256;    // 256..511 -> Wq/Wk
  int c2 = threadIdx.x + 512;    // 512..599 -> Wk (tid < 88)
  const float* w0 = Wq + (size_t)c0 * DIM;
  const float* w1 = (c1 < DIM) ? Wq + (size_t)c1 * DIM : Wk + (size_t)(c1 - DIM) * DIM;
  bool has2 = c2 < 2 * DIM;
  const float* w2 = has2 ? (Wk + (size_t)(c2 - DIM) * DIM) : w0;
  float acc0[RPB], acc1[RPB], acc2[RPB];
#pragma unroll
  for (int r = 0; r < RPB; ++r) { acc0[r] = 0.f; acc1[r] = 0.f; acc2[r] = 0.f; }
  for (int e4 = 0; e4 < DIM / 4; ++e4) {
    float4 wv0 = *(const float4*)(w0 + e4 * 4);
    float4 wv1 = *(const float4*)(w1 + e4 * 4);
    float4 wv2 = *(const float4*)(w2 + e4 * 4);
#pragma unroll
    for (int r = 0; r < RPB; ++r) {
      float4 xv = *(const float4*)(&xs[r][e4 * 4]);
      acc0[r] += wv0.x * xv.x + wv0.y * xv.y + wv0.z * xv.z + wv0.w * xv.w;
      acc1[r] += wv1.x * xv.x + wv1.y * xv.y + wv1.z * xv.z + wv1.w * xv.w;
      acc2[r] += wv2.x * xv.x + wv2.y * xv.y + wv2.z * xv.z + wv2.w * xv.w;
    }
  }
  float bias0 = bq[c0];
  float bias1 = (c1 < DIM) ? bq[c1] : bk[c1 - DIM];
#pragma unroll
  for (int r = 0; r < RPB; ++r) {
    QK[(size_t)(r0 + r) * (2 * DIM) + c0] = acc0[r] + bias0;
    QK[(size_t)(r0 + r) * (2 * DIM) + c1] = acc1[r] + bias1;
  }
  if (has2) {
    float bias2 = bk[c2 - DIM];
#pragma unroll
    for (int r = 0; r < RPB; ++r)
      QK[(size_t)(r0 + r) * (2 * DIM) + c2] = acc2[r] + bias2;
  }
}

// ---------------------------------------------------------------------------
// Kernel 4: per-batch attention + adjacency + exact top-k + GCN rows + output
// ---------------------------------------------------------------------------
__global__ __launch_bounds__(256) void attn_kernel(
    const float* __restrict__ QK, const float* __restrict__ X,
    const float* __restrict__ bq, const float* __restrict__ bk,
    const int* __restrict__ slot_src, const int* __restrict__ out_idx_g,
    const int* __restrict__ aa_len, const float* __restrict__ Wg,
    const float* __restrict__ bg, const float* __restrict__ clause,
    float* __restrict__ out) {
  int b = blockIdx.x, tid = threadIdx.x;
  __shared__ float qh[LG][DK + 1], kh[LG][DK + 1];
  __shared__ float s[LG][LG], adj[LG][LG];
  __shared__ float xc[4][DIM], a2[4][LG];
  __shared__ float rmax[LG], rsum[LG], denomc[4];
  __shared__ int srcs[LG], oidx[LG], nlist[LG];
  __shared__ unsigned int hist[256];
  __shared__ unsigned int sh_prefix;
  __shared__ int sh_need, sh_nneed;

  int length = aa_len[b];
  if (length > LG) length = LG;
  if (tid < LG) {
    srcs[tid] = slot_src[b * LG + tid];
    oidx[tid] = out_idx_g[b * LG + tid];
  }
  __syncthreads();

  if (length <= 1) {  // graph too small: pass clause rows through
    for (int l = 0; l < LG; ++l) {
      int n = oidx[l];
      if (n < 0) continue;
      for (int d = tid; d < DIM; d += 256)
        out[(size_t)n * DIM + d] = clause[(size_t)n * DIM + d];
    }
    return;
  }

  if (tid < LG) { qh[tid][DK] = 0.f; kh[tid][DK] = 0.f; }  // zero-pad dim 75
  for (int i = tid; i < LG * LG; i += 256) (&adj[0][0])[i] = 0.f;
  __syncthreads();

  const float sdk = sqrtf((float)DK);

  for (int h = 0; h < NH; ++h) {
    // gather per-head q/k slices; zero slots use the bias (exact reference value)
    for (int i = tid; i < LG * DK; i += 256) {
      int l = i / DK, d = i - l * DK;
      int src = srcs[l];
      float qv, kv;
      if (src >= 0) {
        qv = QK[(size_t)src * (2 * DIM) + h * DK + d];
        kv = QK[(size_t)src * (2 * DIM) + DIM + h * DK + d];
      } else {
        qv = bq[h * DK + d];
        kv = bk[h * DK + d];
      }
      qh[l][d] = qv;
      kh[l][d] = kv;
    }
    __syncthreads();

    // scores: 16x8 thread grid, 3x6 micro-tile, float4 over padded 76 dims
    if (tid < 128) {
      int ti = tid >> 3, tj = tid & 7;
      int i0 = ti * 3, j0 = tj * 6;
      float acc[3][6];
#pragma unroll
      for (int a = 0; a < 3; ++a)
#pragma unroll
        for (int c = 0; c < 6; ++c) acc[a][c] = 0.f;
      for (int d4 = 0; d4 < (DK + 1) / 4; ++d4) {
        float4 qv[3], kv[6];
#pragma unroll
        for (int a = 0; a < 3; ++a) qv[a] = *(const float4*)(&qh[i0 + a][d4 * 4]);
#pragma unroll
        for (int c = 0; c < 6; ++c) kv[c] = *(const float4*)(&kh[j0 + c][d4 * 4]);
#pragma unroll
        for (int a = 0; a < 3; ++a)
#pragma unroll
          for (int c = 0; c < 6; ++c)
            acc[a][c] += qv[a].x * kv[c].x + qv[a].y * kv[c].y +
                         qv[a].z * kv[c].z + qv[a].w * kv[c].w;
      }
#pragma unroll
      for (int a = 0; a < 3; ++a)
#pragma unroll
        for (int c = 0; c < 6; ++c) {
          int i = i0 + a, j = j0 + c;
          s[i][j] = (j < length) ? (acc[a][c] / sdk) : -1e9f;
        }
    }
    __syncthreads();

    if (tid < length) {
      float mx = s[tid][0];
      for (int j = 1; j < LG; ++j) mx = fmaxf(mx, s[tid][j]);
      rmax[tid] = mx;
    }
    __syncthreads();
    for (int idx = tid; idx < LG * LG; idx += 256) {
      int i = idx / LG;
      if (i < length) (&s[0][0])[idx] = expf((&s[0][0])[idx] - rmax[i]);
    }
    __syncthreads();
    if (tid < length) {
      float sm = 0.f;
      for (int j = 0; j < LG; ++j) sm += s[tid][j];
      rsum[tid] = sm;
    }
    __syncthreads();
    for (int idx = tid; idx < LG * LG; idx += 256) {
      int i = idx / LG;
      if (i < length) (&adj[0][0])[idx] += (&s[0][0])[idx] / rsum[i];
    }
    __syncthreads();
  }

  // mean over heads, diag=1 on valid rows, invalid rows stay zero
  for (int idx = tid; idx < LG * LG; idx += 256) {
    int i = idx / LG, j = idx - i * LG;
    float v = (&adj[0][0])[idx] * 0.25f;
    if (i == j) v = (i < length) ? 1.0f : 0.0f;
    (&adj[0][0])[idx] = v;
  }
  __syncthreads();

  // exact 96th-largest via 4-pass radix select on float bits (all values >= 0)
  unsigned int prefix = 0;
  int need = KTOP;
  for (int p = 24; p >= 0; p -= 8) {
    hist[tid] = 0u;
    __syncthreads();
#pragma unroll
    for (int v = 0; v < 9; ++v) {  // 9*256 = 2304 = 48*48
      unsigned int bits = __float_as_uint((&adj[0][0])[v * 256 + tid]);
      bool match = (p == 24) || ((bits >> (p + 8)) == (prefix >> (p + 8)));
      if (match) atomicAdd(&hist[(bits >> p) & 255u], 1u);
    }
    __syncthreads();
    if (tid == 0) {
      int cum = 0, nd = need;
      unsigned int bsel = 0;
      for (int bb = 255; bb >= 0; --bb) {
        cum += (int)hist[bb];
        if (cum >= nd) {
          bsel = (unsigned int)bb;
          nd -= (cum - (int)hist[bb]);
          break;
        }
      }
      sh_prefix = prefix | (bsel << p);
      sh_need = nd;
    }
    __syncthreads();
    prefix = sh_prefix;
    need = sh_need;
  }
  const float kth = __uint_as_float(prefix);

  // rows needed for output (AS-scatter destinations)
  if (tid == 0) sh_nneed = 0;
  __syncthreads();
  if (tid < LG && oidx[tid] >= 0) {
    int pos = atomicAdd(&sh_nneed, 1);
    nlist[pos] = tid;
  }
  __syncthreads();
  int nneed = sh_nneed;

  for (int c0 = 0; c0 < nneed; c0 += 4) {
    int nc = nneed - c0;
    if (nc > 4) nc = 4;
    // adj2 rows: sel = (a>=kth)+(a^T>=kth), diag forced 1
    if (tid < nc * LG) {
      int r = tid / LG, j = tid - (tid / LG) * LG;
      int i = nlist[c0 + r];
      float aij = adj[i][j];
      float v;
      if (j == i) v = aij;
      else {
        float selv = (aij >= kth ? 1.f : 0.f) + (adj[j][i] >= kth ? 1.f : 0.f);
        v = selv * aij;
      }
      a2[r][j] = v;
    }
    __syncthreads();
    if (tid < nc) {
      float sm = 0.f;
      for (int j = 0; j < LG; ++j) sm += a2[tid][j];
      denomc[tid] = sm + 1.f;
    }
    __syncthreads();
    // x = sum_j adj2[i,j] * inner[b,j,:]  (only non-zero slots contribute)
    for (int r = 0; r < nc; ++r) {
      for (int d = tid; d < DIM; d += 256) {
        float acc = 0.f;
        for (int j = 0; j < LG; ++j) {
          float a = a2[r][j];
          int src = srcs[j];
          if (src >= 0 && a != 0.f) acc += a * X[(size_t)src * DIM + d];
        }
        xc[r][d] = acc;
      }
    }
    __syncthreads();
    // y = relu((x @ Wg^T + bg) / denom) -> out rows
    for (int c = tid; c < DIM; c += 256) {
      const float* w = Wg + (size_t)c * DIM;
      float acc[4] = {0.f, 0.f, 0.f, 0.f};
      for (int e4 = 0; e4 < DIM / 4; ++e4) {
        float4 wv = *(const float4*)(w + e4 * 4);
#pragma unroll
        for (int r = 0; r < 4; ++r) {
          float4 xv = *(const float4*)(&xc[r][e4 * 4]);
          acc[r] += wv.x * xv.x + wv.y * xv.y + wv.z * xv.z + wv.w * xv.w;
        }
      }
      float bgc = bg[c];
#pragma unroll
      for (int r = 0; r < 4; ++r) {
        if (r < nc) {
          int n = oidx[nlist[c0 + r]];
          out[(size_t)n * DIM + c] = fmaxf((acc[r] + bgc) / denomc[r], 0.f);
        }
      }
    }
    __syncthreads();
  }
}

// ---------------------------------------------------------------------------
extern "C" void kernel_launch(void* const* d_in, const int* in_sizes, int n_in,
                              void* d_out, int out_size, void* d_ws, size_t ws_size,
                              hipStream_t stream) {
  (void)in_sizes; (void)n_in; (void)out_size; (void)ws_size;
  const float* input_embed = (const float*)d_in[0];
  const float* clause      = (const float*)d_in[1];
  const float* aa_mask     = (const float*)d_in[2];
  const int*   aa_len      = (const int*)d_in[3];
  const int*   map_AA      = (const int*)d_in[4];
  const int*   map_AA_idx  = (const int*)d_in[5];
  const int*   map_AS      = (const int*)d_in[6];
  const int*   map_AS_idx  = (const int*)d_in[7];
  const float* Wq = (const float*)d_in[8];
  const float* bq = (const float*)d_in[9];
  const float* Wk = (const float*)d_in[10];
  const float* bk = (const float*)d_in[11];
  const float* Wg = (const float*)d_in[12];
  const float* bg = (const float*)d_in[13];
  float* out = (float*)d_out;

  float* X  = (float*)d_ws;                         // 4096*300 f32
  float* QK = X + (size_t)(NA + NC) * DIM;          // 4096*600 f32
  int* slot_src = (int*)(QK + (size_t)(NA + NC) * 2 * DIM);  // 512*48 i32
  int* out_idx  = slot_src + B_SZ * LG;                      // 512*48 i32

  hipMemsetAsync(slot_src, 0xFF, (size_t)B_SZ * LG * sizeof(int) * 2, stream);
  aspect_kernel<<<NA, 256, 0, stream>>>(input_embed, aa_mask, map_AA, map_AA_idx,
                                        X, slot_src);
  clause_kernel<<<NC, 256, 0, stream>>>(clause, map_AS, map_AS_idx, X, slot_src,
                                        out_idx);
  qk_kernel<<<(NA + NC) / RPB, 256, 0, stream>>>(X, Wq, bq, Wk, bk, QK);
  attn_kernel<<<B_SZ, 256, 0, stream>>>(QK, X, bq, bk, slot_src, out_idx, aa_len,
                                        Wg, bg, clause, out);
}

// Round 3
// 297.019 us; speedup vs baseline: 1.0792x; 1.0792x over previous
//
#include <hip/hip_runtime.h>
#include <math.h>

#define B_SZ 512
#define LG 48
#define T_LEN 128
#define DIM 300
#define NA 2048
#define NC 2048
#define NH 4
#define DK 75
#define KTOP 96
#define RPB 16
#define RPB5 8
#define ACAP 16

// ---------------------------------------------------------------------------
// K0: register aspect slots (collision-free; atomicMax vs -1 init) and build
// per-sentence aspect lists for the grouped gather.
// ---------------------------------------------------------------------------
__global__ __launch_bounds__(256) void build_kernel(
    const int* __restrict__ mapAA, const int* __restrict__ mapAAi,
    int* __restrict__ slot_src, int* __restrict__ acnt, int* __restrict__ alist) {
  int n = blockIdx.x * 256 + threadIdx.x;
  if (n >= NA) return;
  int b = mapAA[n];
  atomicMax(&slot_src[b * LG + mapAAi[n]], n);
  int pos = atomicAdd(&acnt[b], 1);
  if (pos < ACAP) alist[b * ACAP + pos] = n;
}

// ---------------------------------------------------------------------------
// K1: grouped aspect embedding. One block per sentence; token tile read once
// from HBM, reused by all aspects of the sentence. t-ascending fma order is
// identical to the round-1 (passing) per-aspect kernel.
// ---------------------------------------------------------------------------
__global__ __launch_bounds__(256) void aspect_kernel(
    const float* __restrict__ embed, const float* __restrict__ mask,
    const int* __restrict__ acnt, const int* __restrict__ alist,
    float* __restrict__ X) {
  int b = blockIdx.x;
  int na = acnt[b]; if (na > ACAP) na = ACAP;
  if (na == 0) return;
  __shared__ float mLds[ACAP][T_LEN];
  __shared__ float4 eLds[32][DK];
  int tid = threadIdx.x;
  for (int i = tid; i < na * T_LEN; i += 256) {
    int k = i / T_LEN, t = i - k * T_LEN;
    mLds[k][t] = mask[(size_t)alist[b * ACAP + k] * T_LEN + t];
  }
  int nw = na * DK;
  int i0 = tid, i1 = tid + 256;
  int k0 = i0 / DK, d0 = i0 - k0 * DK;
  int k1 = i1 / DK, d1 = i1 - k1 * DK;
  float4 a0 = {0, 0, 0, 0}, a1 = {0, 0, 0, 0};
  const float4* e4 = (const float4*)(embed + (size_t)b * T_LEN * DIM);
  for (int t0 = 0; t0 < T_LEN; t0 += 32) {
    __syncthreads();
    for (int i = tid; i < 32 * DK; i += 256) {
      int t = i / DK, d = i - t * DK;
      eLds[t][d] = e4[(size_t)(t0 + t) * DK + d];
    }
    __syncthreads();
#pragma unroll
    for (int t = 0; t < 32; ++t) {
      if (i0 < nw) {
        float m = mLds[k0][t0 + t]; float4 ev = eLds[t][d0];
        a0.x += m * ev.x; a0.y += m * ev.y; a0.z += m * ev.z; a0.w += m * ev.w;
      }
      if (i1 < nw) {
        float m = mLds[k1][t0 + t]; float4 ev = eLds[t][d1];
        a1.x += m * ev.x; a1.y += m * ev.y; a1.z += m * ev.z; a1.w += m * ev.w;
      }
    }
  }
  if (i0 < nw) ((float4*)(X + (size_t)alist[b * ACAP + k0] * DIM))[d0] = a0;
  if (i1 < nw) ((float4*)(X + (size_t)alist[b * ACAP + k1] * DIM))[d1] = a1;
}

// ---------------------------------------------------------------------------
// K2: clause rows -> X[NA+n]; slot registration (NA+n always beats aspects).
// ---------------------------------------------------------------------------
__global__ __launch_bounds__(128) void clause_kernel(
    const float* __restrict__ clause, const int* __restrict__ mapAS,
    const int* __restrict__ mapASi, float* __restrict__ X,
    int* __restrict__ slot_src) {
  int n = blockIdx.x, t = threadIdx.x;
  const float4* src = (const float4*)(clause + (size_t)n * DIM);
  float4* dst = (float4*)(X + (size_t)(NA + n) * DIM);
  if (t < DIM / 4) dst[t] = src[t];
  if (t == 96) atomicMax(&slot_src[mapAS[n] * LG + mapASi[n]], NA + n);
}

// ---------------------------------------------------------------------------
// K3: QK projection over compact rows (unchanged from round 1, passed).
// ---------------------------------------------------------------------------
__global__ __launch_bounds__(256) void qk_kernel(
    const float* __restrict__ X, const float* __restrict__ Wq,
    const float* __restrict__ bq, const float* __restrict__ Wk,
    const float* __restrict__ bk, float* __restrict__ QK) {
  int r0 = blockIdx.x * RPB;
  __shared__ float xs[RPB][DIM];
  for (int i = threadIdx.x; i < RPB * DIM; i += 256) {
    int r = i / DIM;
    xs[r][i - r * DIM] = X[(size_t)r0 * DIM + i];
  }
  __syncthreads();
  int c0 = threadIdx.x;
  int c1 = threadIdx.x + 256;
  int c2 = threadIdx.x + 512;
  const float* w0 = Wq + (size_t)c0 * DIM;
  const float* w1 = (c1 < DIM) ? Wq + (size_t)c1 * DIM : Wk + (size_t)(c1 - DIM) * DIM;
  bool has2 = c2 < 2 * DIM;
  const float* w2 = has2 ? (Wk + (size_t)(c2 - DIM) * DIM) : w0;
  float acc0[RPB], acc1[RPB], acc2[RPB];
#pragma unroll
  for (int r = 0; r < RPB; ++r) { acc0[r] = 0.f; acc1[r] = 0.f; acc2[r] = 0.f; }
  for (int e4 = 0; e4 < DIM / 4; ++e4) {
    float4 wv0 = *(const float4*)(w0 + e4 * 4);
    float4 wv1 = *(const float4*)(w1 + e4 * 4);
    float4 wv2 = *(const float4*)(w2 + e4 * 4);
#pragma unroll
    for (int r = 0; r < RPB; ++r) {
      float4 xv = *(const float4*)(&xs[r][e4 * 4]);
      acc0[r] += wv0.x * xv.x + wv0.y * xv.y + wv0.z * xv.z + wv0.w * xv.w;
      acc1[r] += wv1.x * xv.x + wv1.y * xv.y + wv1.z * xv.z + wv1.w * xv.w;
      acc2[r] += wv2.x * xv.x + wv2.y * xv.y + wv2.z * xv.z + wv2.w * xv.w;
    }
  }
  float bias0 = bq[c0];
  float bias1 = (c1 < DIM) ? bq[c1] : bk[c1 - DIM];
#pragma unroll
  for (int r = 0; r < RPB; ++r) {
    QK[(size_t)(r0 + r) * (2 * DIM) + c0] = acc0[r] + bias0;
    QK[(size_t)(r0 + r) * (2 * DIM) + c1] = acc1[r] + bias1;
  }
  if (has2) {
    float bias2 = bk[c2 - DIM];
#pragma unroll
    for (int r = 0; r < RPB; ++r)
      QK[(size_t)(r0 + r) * (2 * DIM) + c2] = acc2[r] + bias2;
  }
}

// ---------------------------------------------------------------------------
// K4: dense per-batch attention (round-1 value semantics, op-for-op) with:
//  - padded LDS tiles [48][49] (kills the stride-48 bank conflicts)
//  - register binary-search top-k (exact same kth as radix select; no atomics,
//    no serial scan)
//  - GCN x-rows + denom written out; Wg matmul deferred to K5
// ---------------------------------------------------------------------------
__global__ __launch_bounds__(256) void attn_kernel(
    const float* __restrict__ QK, const float* __restrict__ X,
    const float* __restrict__ bq, const float* __restrict__ bk,
    const int* __restrict__ slot_src, const int* __restrict__ aa_len,
    float* __restrict__ xout, float* __restrict__ dng, int* __restrict__ mdg) {
  int b = blockIdx.x, tid = threadIdx.x;
  __shared__ float qh[LG][DK + 1], kh[LG][DK + 1];
  __shared__ float s[LG][LG + 1], adj[LG][LG + 1];
  __shared__ float rmax[LG], rsum[LG];
  __shared__ float coef[4][LG], denomc[4];
  __shared__ int srcs[LG], nlist[LG];
  __shared__ int wsum4[4];
  __shared__ int sh_nneed;

  int length = aa_len[b];
  if (length > LG) length = LG;
  if (tid < LG) srcs[tid] = slot_src[b * LG + tid];
  __syncthreads();

  // output rows = slots last-written by a clause (src >= NA); wave-0 ballot
  if (tid < 64) {
    bool isneed = (tid < LG) && (srcs[tid] >= NA);
    unsigned long long nm = __ballot(isneed);
    if (isneed) nlist[__popcll(nm & ((1ull << tid) - 1ull))] = tid;
    if (tid == 0) sh_nneed = __popcll(nm);
  }
  __syncthreads();
  int nneed = sh_nneed;

  if (length <= 1) {  // whole batch passes clause rows through
    if (tid < nneed) mdg[srcs[nlist[tid]] - NA] = 0;
    return;
  }

  if (tid < LG) { qh[tid][DK] = 0.f; kh[tid][DK] = 0.f; }  // zero-pad dim 75
  for (int e = tid; e < LG * LG; e += 256) adj[e / LG][e - (e / LG) * LG] = 0.f;
  __syncthreads();

  const float sdk = sqrtf((float)DK);

  for (int h = 0; h < NH; ++h) {
    // gather per-head q/k slices; zero slots use the bias (reference-exact)
    for (int i = tid; i < LG * DK; i += 256) {
      int l = i / DK, d = i - (i / DK) * DK;
      int src = srcs[l];
      float qv, kv;
      if (src >= 0) {
        qv = QK[(size_t)src * (2 * DIM) + h * DK + d];
        kv = QK[(size_t)src * (2 * DIM) + DIM + h * DK + d];
      } else {
        qv = bq[h * DK + d];
        kv = bk[h * DK + d];
      }
      qh[l][d] = qv;
      kh[l][d] = kv;
    }
    __syncthreads();

    // scores: 16x8 thread grid, 3x6 micro-tile, float4 over padded 76 dims
    if (tid < 128) {
      int ti = tid >> 3, tj = tid & 7;
      int i0 = ti * 3, j0 = tj * 6;
      float acc[3][6];
#pragma unroll
      for (int a = 0; a < 3; ++a)
#pragma unroll
        for (int c = 0; c < 6; ++c) acc[a][c] = 0.f;
      for (int d4 = 0; d4 < (DK + 1) / 4; ++d4) {
        float4 qv[3], kv[6];
#pragma unroll
        for (int a = 0; a < 3; ++a) qv[a] = *(const float4*)(&qh[i0 + a][d4 * 4]);
#pragma unroll
        for (int c = 0; c < 6; ++c) kv[c] = *(const float4*)(&kh[j0 + c][d4 * 4]);
#pragma unroll
        for (int a = 0; a < 3; ++a)
#pragma unroll
          for (int c = 0; c < 6; ++c)
            acc[a][c] += qv[a].x * kv[c].x + qv[a].y * kv[c].y +
                         qv[a].z * kv[c].z + qv[a].w * kv[c].w;
      }
#pragma unroll
      for (int a = 0; a < 3; ++a)
#pragma unroll
        for (int c = 0; c < 6; ++c) {
          int i = i0 + a, j = j0 + c;
          s[i][j] = (j < length) ? (acc[a][c] / sdk) : -1e9f;
        }
    }
    __syncthreads();

    if (tid < length) {
      float mx = s[tid][0];
      for (int j = 1; j < LG; ++j) mx = fmaxf(mx, s[tid][j]);
      rmax[tid] = mx;
    }
    __syncthreads();
    for (int e = tid; e < LG * LG; e += 256) {
      int i = e / LG, j = e - (e / LG) * LG;
      if (i < length) s[i][j] = expf(s[i][j] - rmax[i]);
    }
    __syncthreads();
    if (tid < length) {
      float sm = 0.f;
      for (int j = 0; j < LG; ++j) sm += s[tid][j];
      rsum[tid] = sm;
    }
    __syncthreads();
    for (int e = tid; e < LG * LG; e += 256) {
      int i = e / LG, j = e - (e / LG) * LG;
      if (i < length) adj[i][j] += s[i][j] / rsum[i];
    }
    __syncthreads();
  }

  // mean over heads, diag=1 on valid rows, invalid rows stay zero
  for (int e = tid; e < LG * LG; e += 256) {
    int i = e / LG, j = e - (e / LG) * LG;
    float v = adj[i][j] * 0.25f;
    if (i == j) v = (i < length) ? 1.0f : 0.0f;
    adj[i][j] = v;
  }
  __syncthreads();

  // exact 96th-largest: binary search on float bits (all values >= 0),
  // 9 values per thread in registers, block reduce per probe
  unsigned int vb[9];
#pragma unroll
  for (int v = 0; v < 9; ++v) {
    int e = v * 256 + tid;  // 0..2303
    vb[v] = __float_as_uint(adj[e / LG][e - (e / LG) * LG]);
  }
  unsigned int cur = 0u;
  int lid = tid & 63, wid = tid >> 6;
  for (int bit = 30; bit >= 0; --bit) {
    unsigned int cand = cur | (1u << bit);
    int c = 0;
#pragma unroll
    for (int v = 0; v < 9; ++v) c += (vb[v] >= cand) ? 1 : 0;
    c += __shfl_xor(c, 32); c += __shfl_xor(c, 16);
    c += __shfl_xor(c, 8);  c += __shfl_xor(c, 4);
    c += __shfl_xor(c, 2);  c += __shfl_xor(c, 1);
    if (lid == 0) wsum4[wid] = c;
    __syncthreads();
    int tot = wsum4[0] + wsum4[1] + wsum4[2] + wsum4[3];
    if (tot >= KTOP) cur = cand;
    __syncthreads();
  }
  const float kth = __uint_as_float(cur);

  // GCN input rows + denominators for the needed (clause) slots
  for (int c0 = 0; c0 < nneed; c0 += 4) {
    int nc = nneed - c0;
    if (nc > 4) nc = 4;
    if (tid < nc * LG) {
      int r = tid / LG, j = tid - (tid / LG) * LG;
      int i = nlist[c0 + r];
      float aij = adj[i][j];
      float v;
      if (j == i) v = aij;
      else {
        float selv = (aij >= kth ? 1.f : 0.f) + (adj[j][i] >= kth ? 1.f : 0.f);
        v = selv * aij;
      }
      coef[r][j] = v;
    }
    __syncthreads();
    if (tid < nc) {
      float sm = 0.f;
      for (int j = 0; j < LG; ++j) sm += coef[tid][j];
      denomc[tid] = sm + 1.f;
    }
    __syncthreads();
    // x = sum_j adj2[i,j] * inner[b,j,:]  (zero slots contribute exactly 0)
    for (int w = tid; w < nc * (DIM / 4); w += 256) {
      int r = w / (DIM / 4), d4 = w - (w / (DIM / 4)) * (DIM / 4);
      float4 acc = {0.f, 0.f, 0.f, 0.f};
      for (int j = 0; j < LG; ++j) {
        int src = srcs[j];
        if (src >= 0) {
          float a = coef[r][j];
          float4 xv = ((const float4*)(X + (size_t)src * DIM))[d4];
          acc.x += a * xv.x; acc.y += a * xv.y;
          acc.z += a * xv.z; acc.w += a * xv.w;
        }
      }
      int n = srcs[nlist[c0 + r]] - NA;
      ((float4*)(xout + (size_t)n * DIM))[d4] = acc;
    }
    if (tid < nc) {
      int n = srcs[nlist[c0 + tid]] - NA;
      mdg[n] = 1;
      dng[n] = denomc[tid];
    }
    __syncthreads();
  }
}

// ---------------------------------------------------------------------------
// K5: y = relu((x @ Wg^T + bg)/dn) or clause passthrough. x staged from d_out
// (aliased) into LDS before overwrite; same dot order as round-1 epilogue.
// ---------------------------------------------------------------------------
__global__ __launch_bounds__(256) void gcn_kernel(
    const float* __restrict__ dng, const int* __restrict__ mdg,
    const float* __restrict__ Wg, const float* __restrict__ bg,
    const float* __restrict__ clause, float* __restrict__ out) {
  int r0 = blockIdx.x * RPB5;
  int tid = threadIdx.x;
  __shared__ float xs[RPB5][DIM];
  __shared__ float dnL[RPB5];
  __shared__ int mdL[RPB5];
  for (int i = tid; i < RPB5 * DIM; i += 256) {
    int r = i / DIM;
    xs[r][i - r * DIM] = out[(size_t)(r0 + r) * DIM + (i - r * DIM)];
  }
  if (tid < RPB5) { dnL[tid] = dng[r0 + tid]; mdL[tid] = mdg[r0 + tid]; }
  __syncthreads();
  int c0 = tid, c1 = tid + 256;
  const float4* w0 = (const float4*)(Wg + (size_t)c0 * DIM);
  const float4* w1 = (c1 < DIM) ? (const float4*)(Wg + (size_t)c1 * DIM) : w0;
  float acc0[RPB5], acc1[RPB5];
#pragma unroll
  for (int r = 0; r < RPB5; ++r) { acc0[r] = 0.f; acc1[r] = 0.f; }
  for (int e = 0; e < DIM / 4; ++e) {
    float4 wa = w0[e], wb = w1[e];
#pragma unroll
    for (int r = 0; r < RPB5; ++r) {
      float4 xv = ((const float4*)xs[r])[e];
      acc0[r] += wa.x * xv.x + wa.y * xv.y + wa.z * xv.z + wa.w * xv.w;
      acc1[r] += wb.x * xv.x + wb.y * xv.y + wb.z * xv.z + wb.w * xv.w;
    }
  }
  float bg0 = bg[c0];
  float bg1 = (c1 < DIM) ? bg[c1] : 0.f;
#pragma unroll
  for (int r = 0; r < RPB5; ++r) {
    int n = r0 + r;
    if (mdL[r]) {
      out[(size_t)n * DIM + c0] = fmaxf((acc0[r] + bg0) / dnL[r], 0.f);
      if (c1 < DIM) out[(size_t)n * DIM + c1] = fmaxf((acc1[r] + bg1) / dnL[r], 0.f);
    } else {
      out[(size_t)n * DIM + c0] = clause[(size_t)n * DIM + c0];
      if (c1 < DIM) out[(size_t)n * DIM + c1] = clause[(size_t)n * DIM + c1];
    }
  }
}

// ---------------------------------------------------------------------------
extern "C" void kernel_launch(void* const* d_in, const int* in_sizes, int n_in,
                              void* d_out, int out_size, void* d_ws, size_t ws_size,
                              hipStream_t stream) {
  (void)in_sizes; (void)n_in; (void)out_size; (void)ws_size;
  const float* input_embed = (const float*)d_in[0];
  const float* clause      = (const float*)d_in[1];
  const float* aa_mask     = (const float*)d_in[2];
  const int*   aa_len      = (const int*)d_in[3];
  const int*   map_AA      = (const int*)d_in[4];
  const int*   map_AA_idx  = (const int*)d_in[5];
  const int*   map_AS      = (const int*)d_in[6];
  const int*   map_AS_idx  = (const int*)d_in[7];
  const float* Wq = (const float*)d_in[8];
  const float* bq = (const float*)d_in[9];
  const float* Wk = (const float*)d_in[10];
  const float* bk = (const float*)d_in[11];
  const float* Wg = (const float*)d_in[12];
  const float* bg = (const float*)d_in[13];
  float* out = (float*)d_out;

  float* X  = (float*)d_ws;                                  // 4096*300
  float* QK = X + (size_t)(NA + NC) * DIM;                   // 4096*600
  int* slot_src = (int*)(QK + (size_t)(NA + NC) * 2 * DIM);  // 512*48
  int* acnt = slot_src + B_SZ * LG;                          // 512
  int* alist = acnt + B_SZ;                                  // 512*16 (freed after K1)
  float* dng = (float*)alist;                                // 2048 (aliases alist)
  int* mdg = (int*)(dng + NC);                               // 2048 (aliases alist)

  hipMemsetAsync(slot_src, 0xFF, (size_t)B_SZ * LG * sizeof(int), stream);
  hipMemsetAsync(acnt, 0x00, (size_t)B_SZ * sizeof(int), stream);
  build_kernel<<<(NA + 255) / 256, 256, 0, stream>>>(map_AA, map_AA_idx,
                                                     slot_src, acnt, alist);
  clause_kernel<<<NC, 128, 0, stream>>>(clause, map_AS, map_AS_idx, X, slot_src);
  aspect_kernel<<<B_SZ, 256, 0, stream>>>(input_embed, aa_mask, acnt, alist, X);
  qk_kernel<<<(NA + NC) / RPB, 256, 0, stream>>>(X, Wq, bq, Wk, bk, QK);
  attn_kernel<<<B_SZ, 256, 0, stream>>>(QK, X, bq, bk, slot_src, aa_len,
                                        out, dng, mdg);
  gcn_kernel<<<NC / RPB5, 256, 0, stream>>>(dng, mdg, Wg, bg, clause, out);
}

// Round 4
// 275.341 us; speedup vs baseline: 1.1642x; 1.0787x over previous
//
#include <hip/hip_runtime.h>
#include <math.h>

#define B_SZ 512
#define LG 48
#define T_LEN 128
#define DIM 300
#define NA 2048
#define NC 2048
#define NH 4
#define DK 75
#define KTOP 96
#define RPB5 8
#define ACAP 16
#define TM 64
#define TN 128
#define KC 100
#define KS (KC + 4)

// ---------------------------------------------------------------------------
// K0: register aspect slots (collision-free; atomicMax vs -1 init) and build
// per-sentence aspect lists for the grouped gather.
// ---------------------------------------------------------------------------
__global__ __launch_bounds__(256) void build_kernel(
    const int* __restrict__ mapAA, const int* __restrict__ mapAAi,
    int* __restrict__ slot_src, int* __restrict__ acnt, int* __restrict__ alist) {
  int n = blockIdx.x * 256 + threadIdx.x;
  if (n >= NA) return;
  int b = mapAA[n];
  atomicMax(&slot_src[b * LG + mapAAi[n]], n);
  int pos = atomicAdd(&acnt[b], 1);
  if (pos < ACAP) alist[b * ACAP + pos] = n;
}

// ---------------------------------------------------------------------------
// K1: grouped aspect embedding. One block per sentence; token tile read once
// from HBM, reused by all aspects of the sentence. t-ascending fma order is
// identical to the round-1 (passing) per-aspect kernel.
// ---------------------------------------------------------------------------
__global__ __launch_bounds__(256) void aspect_kernel(
    const float* __restrict__ embed, const float* __restrict__ mask,
    const int* __restrict__ acnt, const int* __restrict__ alist,
    float* __restrict__ X) {
  int b = blockIdx.x;
  int na = acnt[b]; if (na > ACAP) na = ACAP;
  if (na == 0) return;
  __shared__ float mLds[ACAP][T_LEN];
  __shared__ float4 eLds[32][DK];
  int tid = threadIdx.x;
  for (int i = tid; i < na * T_LEN; i += 256) {
    int k = i / T_LEN, t = i - k * T_LEN;
    mLds[k][t] = mask[(size_t)alist[b * ACAP + k] * T_LEN + t];
  }
  int nw = na * DK;
  int i0 = tid, i1 = tid + 256;
  int k0 = i0 / DK, d0 = i0 - k0 * DK;
  int k1 = i1 / DK, d1 = i1 - k1 * DK;
  float4 a0 = {0, 0, 0, 0}, a1 = {0, 0, 0, 0};
  const float4* e4 = (const float4*)(embed + (size_t)b * T_LEN * DIM);
  for (int t0 = 0; t0 < T_LEN; t0 += 32) {
    __syncthreads();
    for (int i = tid; i < 32 * DK; i += 256) {
      int t = i / DK, d = i - t * DK;
      eLds[t][d] = e4[(size_t)(t0 + t) * DK + d];
    }
    __syncthreads();
#pragma unroll
    for (int t = 0; t < 32; ++t) {
      if (i0 < nw) {
        float m = mLds[k0][t0 + t]; float4 ev = eLds[t][d0];
        a0.x += m * ev.x; a0.y += m * ev.y; a0.z += m * ev.z; a0.w += m * ev.w;
      }
      if (i1 < nw) {
        float m = mLds[k1][t0 + t]; float4 ev = eLds[t][d1];
        a1.x += m * ev.x; a1.y += m * ev.y; a1.z += m * ev.z; a1.w += m * ev.w;
      }
    }
  }
  if (i0 < nw) ((float4*)(X + (size_t)alist[b * ACAP + k0] * DIM))[d0] = a0;
  if (i1 < nw) ((float4*)(X + (size_t)alist[b * ACAP + k1] * DIM))[d1] = a1;
}

// ---------------------------------------------------------------------------
// K2: clause rows -> X[NA+n]; slot registration (NA+n always beats aspects).
// ---------------------------------------------------------------------------
__global__ __launch_bounds__(128) void clause_kernel(
    const float* __restrict__ clause, const int* __restrict__ mapAS,
    const int* __restrict__ mapASi, float* __restrict__ X,
    int* __restrict__ slot_src) {
  int n = blockIdx.x, t = threadIdx.x;
  const float4* src = (const float4*)(clause + (size_t)n * DIM);
  float4* dst = (float4*)(X + (size_t)(NA + n) * DIM);
  if (t < DIM / 4) dst[t] = src[t];
  if (t == 96) atomicMax(&slot_src[mapAS[n] * LG + mapASi[n]], NA + n);
}

// ---------------------------------------------------------------------------
// K3: QK projection as LDS-tiled GEMM. C[4096][600] = X @ [Wq;Wk]^T + bias.
// Tile 64(M) x 128(N), K-chunk 100, micro-tile 8x4 per thread.
// Accumulation order: k ascending in groups of 4, identical expression shape
// to the round-3 kernel -> (near-)bitwise identical Q/K values.
// ---------------------------------------------------------------------------
__global__ __launch_bounds__(256) void qk_kernel(
    const float* __restrict__ X, const float* __restrict__ Wq,
    const float* __restrict__ bq, const float* __restrict__ Wk,
    const float* __restrict__ bk, float* __restrict__ QK) {
  __shared__ __align__(16) float xs[TM][KS];
  __shared__ __align__(16) float ws[TN][KS];
  int m0 = blockIdx.x * TM, n0 = blockIdx.y * TN;
  int tid = threadIdx.x;
  int ty = tid >> 5;   // 0..7  -> micro rows ty*8 .. ty*8+7
  int tx = tid & 31;   // 0..31 -> micro cols tx*4 .. tx*4+3
  float acc[8][4];
#pragma unroll
  for (int a = 0; a < 8; ++a)
#pragma unroll
    for (int c = 0; c < 4; ++c) acc[a][c] = 0.f;

  for (int kc = 0; kc < DIM; kc += KC) {
    __syncthreads();
    for (int i = tid; i < TM * KC; i += 256) {
      int r = i / KC, k = i - r * KC;
      xs[r][k] = X[(size_t)(m0 + r) * DIM + kc + k];
    }
    for (int i = tid; i < TN * KC; i += 256) {
      int c = i / KC, k = i - c * KC;
      int col = n0 + c;
      float v = 0.f;
      if (col < 2 * DIM) {
        const float* w = (col < DIM) ? (Wq + (size_t)col * DIM)
                                     : (Wk + (size_t)(col - DIM) * DIM);
        v = w[kc + k];
      }
      ws[c][k] = v;
    }
    __syncthreads();
#pragma unroll 5
    for (int kg = 0; kg < KC / 4; ++kg) {
      float4 xv[8], wv[4];
#pragma unroll
      for (int a = 0; a < 8; ++a)
        xv[a] = *(const float4*)(&xs[ty * 8 + a][kg * 4]);
#pragma unroll
      for (int c = 0; c < 4; ++c)
        wv[c] = *(const float4*)(&ws[tx * 4 + c][kg * 4]);
#pragma unroll
      for (int a = 0; a < 8; ++a)
#pragma unroll
        for (int c = 0; c < 4; ++c)
          acc[a][c] += wv[c].x * xv[a].x + wv[c].y * xv[a].y +
                       wv[c].z * xv[a].z + wv[c].w * xv[a].w;
    }
  }

  int colg = n0 + tx * 4;       // group of 4 cols, 4-aligned; 600 % 4 == 0
  if (colg < 2 * DIM) {
    float4 bias;
    bias.x = (colg + 0 < DIM) ? bq[colg + 0] : bk[colg + 0 - DIM];
    bias.y = (colg + 1 < DIM) ? bq[colg + 1] : bk[colg + 1 - DIM];
    bias.z = (colg + 2 < DIM) ? bq[colg + 2] : bk[colg + 2 - DIM];
    bias.w = (colg + 3 < DIM) ? bq[colg + 3] : bk[colg + 3 - DIM];
#pragma unroll
    for (int a = 0; a < 8; ++a) {
      float4 o;
      o.x = acc[a][0] + bias.x;
      o.y = acc[a][1] + bias.y;
      o.z = acc[a][2] + bias.z;
      o.w = acc[a][3] + bias.w;
      *(float4*)(&QK[(size_t)(m0 + ty * 8 + a) * (2 * DIM) + colg]) = o;
    }
  }
}

// ---------------------------------------------------------------------------
// K4: dense per-batch attention (round-1 value semantics, op-for-op) with
// padded LDS tiles, register binary-search top-k, GCN x-rows written out.
// (unchanged from round 3, which passed)
// ---------------------------------------------------------------------------
__global__ __launch_bounds__(256) void attn_kernel(
    const float* __restrict__ QK, const float* __restrict__ X,
    const float* __restrict__ bq, const float* __restrict__ bk,
    const int* __restrict__ slot_src, const int* __restrict__ aa_len,
    float* __restrict__ xout, float* __restrict__ dng, int* __restrict__ mdg) {
  int b = blockIdx.x, tid = threadIdx.x;
  __shared__ float qh[LG][DK + 1], kh[LG][DK + 1];
  __shared__ float s[LG][LG + 1], adj[LG][LG + 1];
  __shared__ float rmax[LG], rsum[LG];
  __shared__ float coef[4][LG], denomc[4];
  __shared__ int srcs[LG], nlist[LG];
  __shared__ int wsum4[4];
  __shared__ int sh_nneed;

  int length = aa_len[b];
  if (length > LG) length = LG;
  if (tid < LG) srcs[tid] = slot_src[b * LG + tid];
  __syncthreads();

  if (tid < 64) {
    bool isneed = (tid < LG) && (srcs[tid] >= NA);
    unsigned long long nm = __ballot(isneed);
    if (isneed) nlist[__popcll(nm & ((1ull << tid) - 1ull))] = tid;
    if (tid == 0) sh_nneed = __popcll(nm);
  }
  __syncthreads();
  int nneed = sh_nneed;

  if (length <= 1) {
    if (tid < nneed) mdg[srcs[nlist[tid]] - NA] = 0;
    return;
  }

  if (tid < LG) { qh[tid][DK] = 0.f; kh[tid][DK] = 0.f; }
  for (int e = tid; e < LG * LG; e += 256) adj[e / LG][e - (e / LG) * LG] = 0.f;
  __syncthreads();

  const float sdk = sqrtf((float)DK);

  for (int h = 0; h < NH; ++h) {
    for (int i = tid; i < LG * DK; i += 256) {
      int l = i / DK, d = i - (i / DK) * DK;
      int src = srcs[l];
      float qv, kv;
      if (src >= 0) {
        qv = QK[(size_t)src * (2 * DIM) + h * DK + d];
        kv = QK[(size_t)src * (2 * DIM) + DIM + h * DK + d];
      } else {
        qv = bq[h * DK + d];
        kv = bk[h * DK + d];
      }
      qh[l][d] = qv;
      kh[l][d] = kv;
    }
    __syncthreads();

    if (tid < 128) {
      int ti = tid >> 3, tj = tid & 7;
      int i0 = ti * 3, j0 = tj * 6;
      float acc[3][6];
#pragma unroll
      for (int a = 0; a < 3; ++a)
#pragma unroll
        for (int c = 0; c < 6; ++c) acc[a][c] = 0.f;
      for (int d4 = 0; d4 < (DK + 1) / 4; ++d4) {
        float4 qv[3], kv[6];
#pragma unroll
        for (int a = 0; a < 3; ++a) qv[a] = *(const float4*)(&qh[i0 + a][d4 * 4]);
#pragma unroll
        for (int c = 0; c < 6; ++c) kv[c] = *(const float4*)(&kh[j0 + c][d4 * 4]);
#pragma unroll
        for (int a = 0; a < 3; ++a)
#pragma unroll
          for (int c = 0; c < 6; ++c)
            acc[a][c] += qv[a].x * kv[c].x + qv[a].y * kv[c].y +
                         qv[a].z * kv[c].z + qv[a].w * kv[c].w;
      }
#pragma unroll
      for (int a = 0; a < 3; ++a)
#pragma unroll
        for (int c = 0; c < 6; ++c) {
          int i = i0 + a, j = j0 + c;
          s[i][j] = (j < length) ? (acc[a][c] / sdk) : -1e9f;
        }
    }
    __syncthreads();

    if (tid < length) {
      float mx = s[tid][0];
      for (int j = 1; j < LG; ++j) mx = fmaxf(mx, s[tid][j]);
      rmax[tid] = mx;
    }
    __syncthreads();
    for (int e = tid; e < LG * LG; e += 256) {
      int i = e / LG, j = e - (e / LG) * LG;
      if (i < length) s[i][j] = expf(s[i][j] - rmax[i]);
    }
    __syncthreads();
    if (tid < length) {
      float sm = 0.f;
      for (int j = 0; j < LG; ++j) sm += s[tid][j];
      rsum[tid] = sm;
    }
    __syncthreads();
    for (int e = tid; e < LG * LG; e += 256) {
      int i = e / LG, j = e - (e / LG) * LG;
      if (i < length) adj[i][j] += s[i][j] / rsum[i];
    }
    __syncthreads();
  }

  for (int e = tid; e < LG * LG; e += 256) {
    int i = e / LG, j = e - (e / LG) * LG;
    float v = adj[i][j] * 0.25f;
    if (i == j) v = (i < length) ? 1.0f : 0.0f;
    adj[i][j] = v;
  }
  __syncthreads();

  unsigned int vb[9];
#pragma unroll
  for (int v = 0; v < 9; ++v) {
    int e = v * 256 + tid;
    vb[v] = __float_as_uint(adj[e / LG][e - (e / LG) * LG]);
  }
  unsigned int cur = 0u;
  int lid = tid & 63, wid = tid >> 6;
  for (int bit = 30; bit >= 0; --bit) {
    unsigned int cand = cur | (1u << bit);
    int c = 0;
#pragma unroll
    for (int v = 0; v < 9; ++v) c += (vb[v] >= cand) ? 1 : 0;
    c += __shfl_xor(c, 32); c += __shfl_xor(c, 16);
    c += __shfl_xor(c, 8);  c += __shfl_xor(c, 4);
    c += __shfl_xor(c, 2);  c += __shfl_xor(c, 1);
    if (lid == 0) wsum4[wid] = c;
    __syncthreads();
    int tot = wsum4[0] + wsum4[1] + wsum4[2] + wsum4[3];
    if (tot >= KTOP) cur = cand;
    __syncthreads();
  }
  const float kth = __uint_as_float(cur);

  for (int c0 = 0; c0 < nneed; c0 += 4) {
    int nc = nneed - c0;
    if (nc > 4) nc = 4;
    if (tid < nc * LG) {
      int r = tid / LG, j = tid - (tid / LG) * LG;
      int i = nlist[c0 + r];
      float aij = adj[i][j];
      float v;
      if (j == i) v = aij;
      else {
        float selv = (aij >= kth ? 1.f : 0.f) + (adj[j][i] >= kth ? 1.f : 0.f);
        v = selv * aij;
      }
      coef[r][j] = v;
    }
    __syncthreads();
    if (tid < nc) {
      float sm = 0.f;
      for (int j = 0; j < LG; ++j) sm += coef[tid][j];
      denomc[tid] = sm + 1.f;
    }
    __syncthreads();
    for (int w = tid; w < nc * (DIM / 4); w += 256) {
      int r = w / (DIM / 4), d4 = w - (w / (DIM / 4)) * (DIM / 4);
      float4 acc = {0.f, 0.f, 0.f, 0.f};
      for (int j = 0; j < LG; ++j) {
        int src = srcs[j];
        if (src >= 0) {
          float a = coef[r][j];
          float4 xv = ((const float4*)(X + (size_t)src * DIM))[d4];
          acc.x += a * xv.x; acc.y += a * xv.y;
          acc.z += a * xv.z; acc.w += a * xv.w;
        }
      }
      int n = srcs[nlist[c0 + r]] - NA;
      ((float4*)(xout + (size_t)n * DIM))[d4] = acc;
    }
    if (tid < nc) {
      int n = srcs[nlist[c0 + tid]] - NA;
      mdg[n] = 1;
      dng[n] = denomc[tid];
    }
    __syncthreads();
  }
}

// ---------------------------------------------------------------------------
// K5: y = relu((x @ Wg^T + bg)/dn) or clause passthrough (unchanged).
// ---------------------------------------------------------------------------
__global__ __launch_bounds__(256) void gcn_kernel(
    const float* __restrict__ dng, const int* __restrict__ mdg,
    const float* __restrict__ Wg, const float* __restrict__ bg,
    const float* __restrict__ clause, float* __restrict__ out) {
  int r0 = blockIdx.x * RPB5;
  int tid = threadIdx.x;
  __shared__ float xs[RPB5][DIM];
  __shared__ float dnL[RPB5];
  __shared__ int mdL[RPB5];
  for (int i = tid; i < RPB5 * DIM; i += 256) {
    int r = i / DIM;
    xs[r][i - r * DIM] = out[(size_t)(r0 + r) * DIM + (i - r * DIM)];
  }
  if (tid < RPB5) { dnL[tid] = dng[r0 + tid]; mdL[tid] = mdg[r0 + tid]; }
  __syncthreads();
  int c0 = tid, c1 = tid + 256;
  const float4* w0 = (const float4*)(Wg + (size_t)c0 * DIM);
  const float4* w1 = (c1 < DIM) ? (const float4*)(Wg + (size_t)c1 * DIM) : w0;
  float acc0[RPB5], acc1[RPB5];
#pragma unroll
  for (int r = 0; r < RPB5; ++r) { acc0[r] = 0.f; acc1[r] = 0.f; }
  for (int e = 0; e < DIM / 4; ++e) {
    float4 wa = w0[e], wb = w1[e];
#pragma unroll
    for (int r = 0; r < RPB5; ++r) {
      float4 xv = ((const float4*)xs[r])[e];
      acc0[r] += wa.x * xv.x + wa.y * xv.y + wa.z * xv.z + wa.w * xv.w;
      acc1[r] += wb.x * xv.x + wb.y * xv.y + wb.z * xv.z + wb.w * xv.w;
    }
  }
  float bg0 = bg[c0];
  float bg1 = (c1 < DIM) ? bg[c1] : 0.f;
#pragma unroll
  for (int r = 0; r < RPB5; ++r) {
    int n = r0 + r;
    if (mdL[r]) {
      out[(size_t)n * DIM + c0] = fmaxf((acc0[r] + bg0) / dnL[r], 0.f);
      if (c1 < DIM) out[(size_t)n * DIM + c1] = fmaxf((acc1[r] + bg1) / dnL[r], 0.f);
    } else {
      out[(size_t)n * DIM + c0] = clause[(size_t)n * DIM + c0];
      if (c1 < DIM) out[(size_t)n * DIM + c1] = clause[(size_t)n * DIM + c1];
    }
  }
}

// ---------------------------------------------------------------------------
extern "C" void kernel_launch(void* const* d_in, const int* in_sizes, int n_in,
                              void* d_out, int out_size, void* d_ws, size_t ws_size,
                              hipStream_t stream) {
  (void)in_sizes; (void)n_in; (void)out_size; (void)ws_size;
  const float* input_embed = (const float*)d_in[0];
  const float* clause      = (const float*)d_in[1];
  const float* aa_mask     = (const float*)d_in[2];
  const int*   aa_len      = (const int*)d_in[3];
  const int*   map_AA      = (const int*)d_in[4];
  const int*   map_AA_idx  = (const int*)d_in[5];
  const int*   map_AS      = (const int*)d_in[6];
  const int*   map_AS_idx  = (const int*)d_in[7];
  const float* Wq = (const float*)d_in[8];
  const float* bq = (const float*)d_in[9];
  const float* Wk = (const float*)d_in[10];
  const float* bk = (const float*)d_in[11];
  const float* Wg = (const float*)d_in[12];
  const float* bg = (const float*)d_in[13];
  float* out = (float*)d_out;

  float* X  = (float*)d_ws;                                  // 4096*300
  float* QK = X + (size_t)(NA + NC) * DIM;                   // 4096*600
  int* slot_src = (int*)(QK + (size_t)(NA + NC) * 2 * DIM);  // 512*48
  int* acnt = slot_src + B_SZ * LG;                          // 512
  int* alist = acnt + B_SZ;                                  // 512*16 (freed after K1)
  float* dng = (float*)alist;                                // 2048 (aliases alist)
  int* mdg = (int*)(dng + NC);                               // 2048 (aliases alist)

  hipMemsetAsync(slot_src, 0xFF, (size_t)B_SZ * LG * sizeof(int), stream);
  hipMemsetAsync(acnt, 0x00, (size_t)B_SZ * sizeof(int), stream);
  build_kernel<<<(NA + 255) / 256, 256, 0, stream>>>(map_AA, map_AA_idx,
                                                     slot_src, acnt, alist);
  clause_kernel<<<NC, 128, 0, stream>>>(clause, map_AS, map_AS_idx, X, slot_src);
  aspect_kernel<<<B_SZ, 256, 0, stream>>>(input_embed, aa_mask, acnt, alist, X);
  dim3 qkgrid(4096 / TM, (2 * DIM + TN - 1) / TN);
  qk_kernel<<<qkgrid, 256, 0, stream>>>(X, Wq, bq, Wk, bk, QK);
  attn_kernel<<<B_SZ, 256, 0, stream>>>(QK, X, bq, bk, slot_src, aa_len,
                                        out, dng, mdg);
  gcn_kernel<<<NC / RPB5, 256, 0, stream>>>(dng, mdg, Wg, bg, clause, out);
}

// Round 5
// 229.144 us; speedup vs baseline: 1.3989x; 1.2016x over previous
//
#include <hip/hip_runtime.h>
#include <math.h>

#define B_SZ 512
#define LG 48
#define T_LEN 128
#define DIM 300
#define NA 2048
#define NC 2048
#define NH 4
#define DK 75
#define KTOP 96
#define RPB5 8
#define ACAP 16
#define TM 64
#define TN 96
#define KC 100
#define QKS 608   // padded QK row: 4 heads x 76 (q) + 4 heads x 76 (k)

// ---------------------------------------------------------------------------
// K0: register aspect slots (atomicMax vs -1 init) + per-sentence aspect lists
// ---------------------------------------------------------------------------
__global__ __launch_bounds__(256) void build_kernel(
    const int* __restrict__ mapAA, const int* __restrict__ mapAAi,
    int* __restrict__ slot_src, int* __restrict__ acnt, int* __restrict__ alist) {
  int n = blockIdx.x * 256 + threadIdx.x;
  if (n >= NA) return;
  int b = mapAA[n];
  atomicMax(&slot_src[b * LG + mapAAi[n]], n);
  int pos = atomicAdd(&acnt[b], 1);
  if (pos < ACAP) alist[b * ACAP + pos] = n;
}

// ---------------------------------------------------------------------------
// K1: grouped aspect embedding (unchanged; passed rounds 2-4)
// ---------------------------------------------------------------------------
__global__ __launch_bounds__(256) void aspect_kernel(
    const float* __restrict__ embed, const float* __restrict__ mask,
    const int* __restrict__ acnt, const int* __restrict__ alist,
    float* __restrict__ X) {
  int b = blockIdx.x;
  int na = acnt[b]; if (na > ACAP) na = ACAP;
  if (na == 0) return;
  __shared__ float mLds[ACAP][T_LEN];
  __shared__ float4 eLds[32][DK];
  int tid = threadIdx.x;
  for (int i = tid; i < na * T_LEN; i += 256) {
    int k = i / T_LEN, t = i - k * T_LEN;
    mLds[k][t] = mask[(size_t)alist[b * ACAP + k] * T_LEN + t];
  }
  int nw = na * DK;
  int i0 = tid, i1 = tid + 256;
  int k0 = i0 / DK, d0 = i0 - k0 * DK;
  int k1 = i1 / DK, d1 = i1 - k1 * DK;
  float4 a0 = {0, 0, 0, 0}, a1 = {0, 0, 0, 0};
  const float4* e4 = (const float4*)(embed + (size_t)b * T_LEN * DIM);
  for (int t0 = 0; t0 < T_LEN; t0 += 32) {
    __syncthreads();
    for (int i = tid; i < 32 * DK; i += 256) {
      int t = i / DK, d = i - t * DK;
      eLds[t][d] = e4[(size_t)(t0 + t) * DK + d];
    }
    __syncthreads();
#pragma unroll
    for (int t = 0; t < 32; ++t) {
      if (i0 < nw) {
        float m = mLds[k0][t0 + t]; float4 ev = eLds[t][d0];
        a0.x += m * ev.x; a0.y += m * ev.y; a0.z += m * ev.z; a0.w += m * ev.w;
      }
      if (i1 < nw) {
        float m = mLds[k1][t0 + t]; float4 ev = eLds[t][d1];
        a1.x += m * ev.x; a1.y += m * ev.y; a1.z += m * ev.z; a1.w += m * ev.w;
      }
    }
  }
  if (i0 < nw) ((float4*)(X + (size_t)alist[b * ACAP + k0] * DIM))[d0] = a0;
  if (i1 < nw) ((float4*)(X + (size_t)alist[b * ACAP + k1] * DIM))[d1] = a1;
}

// ---------------------------------------------------------------------------
// K2: clause rows -> X[NA+n]; slot registration (unchanged)
// ---------------------------------------------------------------------------
__global__ __launch_bounds__(128) void clause_kernel(
    const float* __restrict__ clause, const int* __restrict__ mapAS,
    const int* __restrict__ mapASi, float* __restrict__ X,
    int* __restrict__ slot_src) {
  int n = blockIdx.x, t = threadIdx.x;
  const float4* src = (const float4*)(clause + (size_t)n * DIM);
  float4* dst = (float4*)(X + (size_t)(NA + n) * DIM);
  if (t < DIM / 4) dst[t] = src[t];
  if (t == 96) atomicMax(&slot_src[mapAS[n] * LG + mapASi[n]], NA + n);
}

// ---------------------------------------------------------------------------
// K3: QK GEMM v2. Tile 64(M) x 96(N), KC=100, micro 4x6 with STRIDED cols
// (c = tx + 16*cc) so LDS lane-stride = 100 floats == 4 mod 32 banks ->
// 8 bank-windows x 2 lanes = 2-way = conflict-free. Row stride 100 (no pad).
// Accumulation: groups-of-4 k ascending, 3 chunks of 100 — identical fp
// order to the round-4 kernel (passed). Output written with 608-stride
// per-head-padded layout: q head h at h*76, k head h at 304+h*76.
// ---------------------------------------------------------------------------
__global__ __launch_bounds__(256) void qk_kernel(
    const float* __restrict__ X, const float* __restrict__ Wq,
    const float* __restrict__ bq, const float* __restrict__ Wk,
    const float* __restrict__ bk, float* __restrict__ QK) {
  __shared__ __align__(16) float xs[TM][KC];
  __shared__ __align__(16) float ws[TN][KC];
  int m0 = blockIdx.x * TM, n0 = blockIdx.y * TN;
  int tid = threadIdx.x;
  int ty = tid >> 4;   // 0..15 -> rows ty*4+a
  int tx = tid & 15;   // 0..15 -> cols tx+16*cc
  float acc[4][6];
#pragma unroll
  for (int a = 0; a < 4; ++a)
#pragma unroll
    for (int c = 0; c < 6; ++c) acc[a][c] = 0.f;

  for (int kc = 0; kc < DIM; kc += KC) {
    __syncthreads();
    for (int i = tid; i < TM * (KC / 4); i += 256) {
      int r = i / (KC / 4), g = i - r * (KC / 4);
      *(float4*)&xs[r][g * 4] =
          *(const float4*)&X[(size_t)(m0 + r) * DIM + kc + g * 4];
    }
    for (int i = tid; i < TN * (KC / 4); i += 256) {
      int c = i / (KC / 4), g = i - c * (KC / 4);
      int col = n0 + c;
      float4 v = {0.f, 0.f, 0.f, 0.f};
      if (col < 2 * DIM) {
        const float* w = (col < DIM) ? (Wq + (size_t)col * DIM)
                                     : (Wk + (size_t)(col - DIM) * DIM);
        v = *(const float4*)&w[kc + g * 4];
      }
      *(float4*)&ws[c][g * 4] = v;
    }
    __syncthreads();
#pragma unroll 5
    for (int kg = 0; kg < KC / 4; ++kg) {
      float4 xv[4], wv[6];
#pragma unroll
      for (int a = 0; a < 4; ++a) xv[a] = *(const float4*)&xs[ty * 4 + a][kg * 4];
#pragma unroll
      for (int c = 0; c < 6; ++c) wv[c] = *(const float4*)&ws[tx + 16 * c][kg * 4];
#pragma unroll
      for (int a = 0; a < 4; ++a)
#pragma unroll
        for (int c = 0; c < 6; ++c)
          acc[a][c] += wv[c].x * xv[a].x + wv[c].y * xv[a].y +
                       wv[c].z * xv[a].z + wv[c].w * xv[a].w;
    }
  }

#pragma unroll
  for (int cc = 0; cc < 6; ++cc) {
    int col = n0 + tx + 16 * cc;
    if (col < 2 * DIM) {
      float bias; int off;
      if (col < DIM) { bias = bq[col]; off = col + col / DK; }
      else { int c2 = col - DIM; bias = bk[c2]; off = 304 + c2 + c2 / DK; }
#pragma unroll
      for (int a = 0; a < 4; ++a)
        QK[(size_t)(m0 + ty * 4 + a) * QKS + off] = acc[a][cc] + bias;
    }
  }
}

// ---------------------------------------------------------------------------
// K4: attention v2. float4 gather from padded QK; scores+softmax fully in
// registers (8-lane shfl row reduce — exact for the tie-critical zero rows);
// adj accumulation order identical to round-3 (passed). Top-k binary search
// on one wave, zero barriers inside. adj2/xout epilogue as round 3.
// ---------------------------------------------------------------------------
__global__ __launch_bounds__(256) void attn_kernel(
    const float* __restrict__ QK, const float* __restrict__ X,
    const float* __restrict__ bq, const float* __restrict__ bk,
    const int* __restrict__ slot_src, const int* __restrict__ aa_len,
    float* __restrict__ xout, float* __restrict__ dng, int* __restrict__ mdg) {
  int b = blockIdx.x, tid = threadIdx.x;
  __shared__ __align__(16) float qh[LG][76], kh[LG][76];
  __shared__ float adj[LG][LG + 1];
  __shared__ float coef[4][LG], denomc[4];
  __shared__ int srcs[LG], nlist[LG];
  __shared__ float kthL;
  __shared__ int sh_nneed;

  int length = aa_len[b];
  if (length > LG) length = LG;
  if (tid < LG) srcs[tid] = slot_src[b * LG + tid];
  __syncthreads();

  if (tid < 64) {
    bool isneed = (tid < LG) && (srcs[tid] >= NA);
    unsigned long long nm = __ballot(isneed);
    if (isneed) nlist[__popcll(nm & ((1ull << tid) - 1ull))] = tid;
    if (tid == 0) sh_nneed = __popcll(nm);
  }
  __syncthreads();
  int nneed = sh_nneed;

  if (length <= 1) {
    if (tid < nneed) mdg[srcs[nlist[tid]] - NA] = 0;
    return;
  }

  for (int e = tid; e < LG * LG; e += 256) adj[e / LG][e % LG] = 0.f;

  const float sdk = sqrtf((float)DK);
  int ti = tid >> 3, tj = tid & 7;   // valid for tid < 128
  int i0 = ti * 3, j0 = tj * 6;

  for (int h = 0; h < NH; ++h) {
    // stage q/k head slices as float4 (19 per row-half); pad elem 75 -> 0
    for (int i = tid; i < 2 * LG * 19; i += 256) {
      int half = i / (LG * 19);
      int rem = i - half * (LG * 19);
      int r = rem / 19, g = rem - (rem / 19) * 19;
      int src = srcs[r];
      float4 v;
      if (src >= 0) {
        v = *(const float4*)&QK[(size_t)src * QKS + half * 304 + h * 76 + g * 4];
        if (g == 18) v.w = 0.f;
      } else {
        const float* bias = half ? bk : bq;
        int d0 = g * 4;
        v.x = (d0 + 0 < DK) ? bias[h * DK + d0 + 0] : 0.f;
        v.y = (d0 + 1 < DK) ? bias[h * DK + d0 + 1] : 0.f;
        v.z = (d0 + 2 < DK) ? bias[h * DK + d0 + 2] : 0.f;
        v.w = (d0 + 3 < DK) ? bias[h * DK + d0 + 3] : 0.f;
      }
      float* dst = half ? &kh[r][g * 4] : &qh[r][g * 4];
      *(float4*)dst = v;
    }
    __syncthreads();

    if (tid < 128) {
      float acc[3][6];
#pragma unroll
      for (int a = 0; a < 3; ++a)
#pragma unroll
        for (int c = 0; c < 6; ++c) acc[a][c] = 0.f;
      for (int d4 = 0; d4 < 19; ++d4) {
        float4 qv[3], kv[6];
#pragma unroll
        for (int a = 0; a < 3; ++a) qv[a] = *(const float4*)&qh[i0 + a][d4 * 4];
#pragma unroll
        for (int c = 0; c < 6; ++c) kv[c] = *(const float4*)&kh[j0 + c][d4 * 4];
#pragma unroll
        for (int a = 0; a < 3; ++a)
#pragma unroll
          for (int c = 0; c < 6; ++c)
            acc[a][c] += qv[a].x * kv[c].x + qv[a].y * kv[c].y +
                         qv[a].z * kv[c].z + qv[a].w * kv[c].w;
      }
#pragma unroll
      for (int a = 0; a < 3; ++a) {
        float p[6];
#pragma unroll
        for (int c = 0; c < 6; ++c)
          p[c] = (j0 + c < length) ? (acc[a][c] / sdk) : -1e9f;
        float mx = p[0];
#pragma unroll
        for (int c = 1; c < 6; ++c) mx = fmaxf(mx, p[c]);
        mx = fmaxf(mx, __shfl_xor(mx, 1));
        mx = fmaxf(mx, __shfl_xor(mx, 2));
        mx = fmaxf(mx, __shfl_xor(mx, 4));
        float rs = 0.f;
#pragma unroll
        for (int c = 0; c < 6; ++c) { p[c] = expf(p[c] - mx); rs += p[c]; }
        rs += __shfl_xor(rs, 1);
        rs += __shfl_xor(rs, 2);
        rs += __shfl_xor(rs, 4);
        if (i0 + a < length) {
#pragma unroll
          for (int c = 0; c < 6; ++c) adj[i0 + a][j0 + c] += p[c] / rs;
        }
      }
    }
    __syncthreads();
  }

  // mean over heads, diag=1 on valid rows; rows >= length stay exactly 0
  for (int e = tid; e < LG * LG; e += 256) {
    int i = e / LG, j = e % LG;
    float v = adj[i][j] * 0.25f;
    if (i == j) v = (i < length) ? 1.0f : 0.0f;
    adj[i][j] = v;
  }
  __syncthreads();

  // exact 96th-largest: single-wave binary search, values in registers
  if (tid < 64) {
    unsigned int vb[36];
#pragma unroll
    for (int v = 0; v < 36; ++v) {
      int e = v * 64 + tid;   // 0..2303
      vb[v] = __float_as_uint(adj[e / LG][e % LG]);
    }
    unsigned int cur = 0u;
    for (int bit = 30; bit >= 0; --bit) {
      unsigned int cand = cur | (1u << bit);
      int c = 0;
#pragma unroll
      for (int v = 0; v < 36; ++v) c += (vb[v] >= cand) ? 1 : 0;
      c += __shfl_xor(c, 32); c += __shfl_xor(c, 16);
      c += __shfl_xor(c, 8);  c += __shfl_xor(c, 4);
      c += __shfl_xor(c, 2);  c += __shfl_xor(c, 1);
      if (c >= KTOP) cur = cand;
    }
    if (tid == 0) kthL = __uint_as_float(cur);
  }
  __syncthreads();
  const float kth = kthL;

  // GCN input rows + denominators for the needed (clause) slots
  for (int c0 = 0; c0 < nneed; c0 += 4) {
    int nc = nneed - c0;
    if (nc > 4) nc = 4;
    if (tid < nc * LG) {
      int r = tid / LG, j = tid - (tid / LG) * LG;
      int i = nlist[c0 + r];
      float aij = adj[i][j];
      float v;
      if (j == i) v = aij;
      else {
        float selv = (aij >= kth ? 1.f : 0.f) + (adj[j][i] >= kth ? 1.f : 0.f);
        v = selv * aij;
      }
      coef[r][j] = v;
    }
    __syncthreads();
    if (tid < nc) {
      float sm = 0.f;
      for (int j = 0; j < LG; ++j) sm += coef[tid][j];
      denomc[tid] = sm + 1.f;
    }
    __syncthreads();
    for (int w = tid; w < nc * (DIM / 4); w += 256) {
      int r = w / (DIM / 4), d4 = w - (w / (DIM / 4)) * (DIM / 4);
      float4 acc = {0.f, 0.f, 0.f, 0.f};
      for (int j = 0; j < LG; ++j) {
        int src = srcs[j];
        if (src >= 0) {
          float a = coef[r][j];
          float4 xv = ((const float4*)(X + (size_t)src * DIM))[d4];
          acc.x += a * xv.x; acc.y += a * xv.y;
          acc.z += a * xv.z; acc.w += a * xv.w;
        }
      }
      int n = srcs[nlist[c0 + r]] - NA;
      ((float4*)(xout + (size_t)n * DIM))[d4] = acc;
    }
    if (tid < nc) {
      int n = srcs[nlist[c0 + tid]] - NA;
      mdg[n] = 1;
      dng[n] = denomc[tid];
    }
    __syncthreads();
  }
}

// ---------------------------------------------------------------------------
// K5: y = relu((x @ Wg^T + bg)/dn) or clause passthrough (unchanged)
// ---------------------------------------------------------------------------
__global__ __launch_bounds__(256) void gcn_kernel(
    const float* __restrict__ dng, const int* __restrict__ mdg,
    const float* __restrict__ Wg, const float* __restrict__ bg,
    const float* __restrict__ clause, float* __restrict__ out) {
  int r0 = blockIdx.x * RPB5;
  int tid = threadIdx.x;
  __shared__ float xs[RPB5][DIM];
  __shared__ float dnL[RPB5];
  __shared__ int mdL[RPB5];
  for (int i = tid; i < RPB5 * DIM; i += 256) {
    int r = i / DIM;
    xs[r][i - r * DIM] = out[(size_t)(r0 + r) * DIM + (i - r * DIM)];
  }
  if (tid < RPB5) { dnL[tid] = dng[r0 + tid]; mdL[tid] = mdg[r0 + tid]; }
  __syncthreads();
  int c0 = tid, c1 = tid + 256;
  const float4* w0 = (const float4*)(Wg + (size_t)c0 * DIM);
  const float4* w1 = (c1 < DIM) ? (const float4*)(Wg + (size_t)c1 * DIM) : w0;
  float acc0[RPB5], acc1[RPB5];
#pragma unroll
  for (int r = 0; r < RPB5; ++r) { acc0[r] = 0.f; acc1[r] = 0.f; }
  for (int e = 0; e < DIM / 4; ++e) {
    float4 wa = w0[e], wb = w1[e];
#pragma unroll
    for (int r = 0; r < RPB5; ++r) {
      float4 xv = ((const float4*)xs[r])[e];
      acc0[r] += wa.x * xv.x + wa.y * xv.y + wa.z * xv.z + wa.w * xv.w;
      acc1[r] += wb.x * xv.x + wb.y * xv.y + wb.z * xv.z + wb.w * xv.w;
    }
  }
  float bg0 = bg[c0];
  float bg1 = (c1 < DIM) ? bg[c1] : 0.f;
#pragma unroll
  for (int r = 0; r < RPB5; ++r) {
    int n = r0 + r;
    if (mdL[r]) {
      out[(size_t)n * DIM + c0] = fmaxf((acc0[r] + bg0) / dnL[r], 0.f);
      if (c1 < DIM) out[(size_t)n * DIM + c1] = fmaxf((acc1[r] + bg1) / dnL[r], 0.f);
    } else {
      out[(size_t)n * DIM + c0] = clause[(size_t)n * DIM + c0];
      if (c1 < DIM) out[(size_t)n * DIM + c1] = clause[(size_t)n * DIM + c1];
    }
  }
}

// ---------------------------------------------------------------------------
extern "C" void kernel_launch(void* const* d_in, const int* in_sizes, int n_in,
                              void* d_out, int out_size, void* d_ws, size_t ws_size,
                              hipStream_t stream) {
  (void)in_sizes; (void)n_in; (void)out_size; (void)ws_size;
  const float* input_embed = (const float*)d_in[0];
  const float* clause      = (const float*)d_in[1];
  const float* aa_mask     = (const float*)d_in[2];
  const int*   aa_len      = (const int*)d_in[3];
  const int*   map_AA      = (const int*)d_in[4];
  const int*   map_AA_idx  = (const int*)d_in[5];
  const int*   map_AS      = (const int*)d_in[6];
  const int*   map_AS_idx  = (const int*)d_in[7];
  const float* Wq = (const float*)d_in[8];
  const float* bq = (const float*)d_in[9];
  const float* Wk = (const float*)d_in[10];
  const float* bk = (const float*)d_in[11];
  const float* Wg = (const float*)d_in[12];
  const float* bg = (const float*)d_in[13];
  float* out = (float*)d_out;

  float* X  = (float*)d_ws;                                  // 4096*300
  float* QK = X + (size_t)(NA + NC) * DIM;                   // 4096*608 (padded)
  int* slot_src = (int*)(QK + (size_t)(NA + NC) * QKS);      // 512*48
  int* acnt = slot_src + B_SZ * LG;                          // 512
  int* alist = acnt + B_SZ;                                  // 512*16 (freed after K1)
  float* dng = (float*)alist;                                // 2048 (aliases alist)
  int* mdg = (int*)(dng + NC);                               // 2048 (aliases alist)

  hipMemsetAsync(slot_src, 0xFF, (size_t)B_SZ * LG * sizeof(int), stream);
  hipMemsetAsync(acnt, 0x00, (size_t)B_SZ * sizeof(int), stream);
  build_kernel<<<(NA + 255) / 256, 256, 0, stream>>>(map_AA, map_AA_idx,
                                                     slot_src, acnt, alist);
  clause_kernel<<<NC, 128, 0, stream>>>(clause, map_AS, map_AS_idx, X, slot_src);
  aspect_kernel<<<B_SZ, 256, 0, stream>>>(input_embed, aa_mask, acnt, alist, X);
  dim3 qkgrid((NA + NC) / TM, (2 * DIM + TN - 1) / TN);
  qk_kernel<<<qkgrid, 256, 0, stream>>>(X, Wq, bq, Wk, bk, QK);
  attn_kernel<<<B_SZ, 256, 0, stream>>>(QK, X, bq, bk, slot_src, aa_len,
                                        out, dng, mdg);
  gcn_kernel<<<NC / RPB5, 256, 0, stream>>>(dng, mdg, Wg, bg, clause, out);
}

// Round 6
// 191.440 us; speedup vs baseline: 1.6745x; 1.1970x over previous
//
#include <hip/hip_runtime.h>
#include <math.h>

#define B_SZ 512
#define LG 48
#define T_LEN 128
#define DIM 300
#define NA 2048
#define NC 2048
#define NH 4
#define DK 75
#define KTOP 96
#define ACAP 16
#define TM 64
#define TN 96
#define KC 60
#define QKS 608   // padded QK row: 4 heads x 76 (q) + 4 heads x 76 (k)
#define GTM 32
#define GTN 64
#define GKC 60

// ---------------------------------------------------------------------------
// K0: register aspect slots (atomicMax vs -1 init) + per-sentence aspect lists
// ---------------------------------------------------------------------------
__global__ __launch_bounds__(256) void build_kernel(
    const int* __restrict__ mapAA, const int* __restrict__ mapAAi,
    int* __restrict__ slot_src, int* __restrict__ acnt, int* __restrict__ alist) {
  int n = blockIdx.x * 256 + threadIdx.x;
  if (n >= NA) return;
  int b = mapAA[n];
  atomicMax(&slot_src[b * LG + mapAAi[n]], n);
  int pos = atomicAdd(&acnt[b], 1);
  if (pos < ACAP) alist[b * ACAP + pos] = n;
}

// ---------------------------------------------------------------------------
// K1: grouped aspect embedding (unchanged; passed rounds 2-5)
// ---------------------------------------------------------------------------
__global__ __launch_bounds__(256) void aspect_kernel(
    const float* __restrict__ embed, const float* __restrict__ mask,
    const int* __restrict__ acnt, const int* __restrict__ alist,
    float* __restrict__ X) {
  int b = blockIdx.x;
  int na = acnt[b]; if (na > ACAP) na = ACAP;
  if (na == 0) return;
  __shared__ float mLds[ACAP][T_LEN];
  __shared__ float4 eLds[32][DK];
  int tid = threadIdx.x;
  for (int i = tid; i < na * T_LEN; i += 256) {
    int k = i / T_LEN, t = i - k * T_LEN;
    mLds[k][t] = mask[(size_t)alist[b * ACAP + k] * T_LEN + t];
  }
  int nw = na * DK;
  int i0 = tid, i1 = tid + 256;
  int k0 = i0 / DK, d0 = i0 - k0 * DK;
  int k1 = i1 / DK, d1 = i1 - k1 * DK;
  float4 a0 = {0, 0, 0, 0}, a1 = {0, 0, 0, 0};
  const float4* e4 = (const float4*)(embed + (size_t)b * T_LEN * DIM);
  for (int t0 = 0; t0 < T_LEN; t0 += 32) {
    __syncthreads();
    for (int i = tid; i < 32 * DK; i += 256) {
      int t = i / DK, d = i - t * DK;
      eLds[t][d] = e4[(size_t)(t0 + t) * DK + d];
    }
    __syncthreads();
#pragma unroll
    for (int t = 0; t < 32; ++t) {
      if (i0 < nw) {
        float m = mLds[k0][t0 + t]; float4 ev = eLds[t][d0];
        a0.x += m * ev.x; a0.y += m * ev.y; a0.z += m * ev.z; a0.w += m * ev.w;
      }
      if (i1 < nw) {
        float m = mLds[k1][t0 + t]; float4 ev = eLds[t][d1];
        a1.x += m * ev.x; a1.y += m * ev.y; a1.z += m * ev.z; a1.w += m * ev.w;
      }
    }
  }
  if (i0 < nw) ((float4*)(X + (size_t)alist[b * ACAP + k0] * DIM))[d0] = a0;
  if (i1 < nw) ((float4*)(X + (size_t)alist[b * ACAP + k1] * DIM))[d1] = a1;
}

// ---------------------------------------------------------------------------
// K2: clause rows -> X[NA+n]; slot registration (unchanged)
// ---------------------------------------------------------------------------
__global__ __launch_bounds__(128) void clause_kernel(
    const float* __restrict__ clause, const int* __restrict__ mapAS,
    const int* __restrict__ mapASi, float* __restrict__ X,
    int* __restrict__ slot_src) {
  int n = blockIdx.x, t = threadIdx.x;
  const float4* src = (const float4*)(clause + (size_t)n * DIM);
  float4* dst = (float4*)(X + (size_t)(NA + n) * DIM);
  if (t < DIM / 4) dst[t] = src[t];
  if (t == 96) atomicMax(&slot_src[mapAS[n] * LG + mapASi[n]], NA + n);
}

// ---------------------------------------------------------------------------
// K3: QK GEMM. Tile 64x96, KC=60 (38.4KB LDS -> 4 blocks/CU, was 2 at KC=100).
// Micro 4x6, strided cols (tx+16*cc). fp accumulation order: strictly
// k-ascending groups of 4 — identical to rounds 4/5 (passed).
// ---------------------------------------------------------------------------
__global__ __launch_bounds__(256) void qk_kernel(
    const float* __restrict__ X, const float* __restrict__ Wq,
    const float* __restrict__ bq, const float* __restrict__ Wk,
    const float* __restrict__ bk, float* __restrict__ QK) {
  __shared__ __align__(16) float xs[TM][KC];
  __shared__ __align__(16) float ws[TN][KC];
  int m0 = blockIdx.x * TM, n0 = blockIdx.y * TN;
  int tid = threadIdx.x;
  int ty = tid >> 4;   // 0..15 -> rows ty*4+a
  int tx = tid & 15;   // 0..15 -> cols tx+16*cc
  float acc[4][6];
#pragma unroll
  for (int a = 0; a < 4; ++a)
#pragma unroll
    for (int c = 0; c < 6; ++c) acc[a][c] = 0.f;

  for (int kc = 0; kc < DIM; kc += KC) {
    __syncthreads();
    for (int i = tid; i < TM * (KC / 4); i += 256) {
      int r = i / (KC / 4), g = i - r * (KC / 4);
      *(float4*)&xs[r][g * 4] =
          *(const float4*)&X[(size_t)(m0 + r) * DIM + kc + g * 4];
    }
    for (int i = tid; i < TN * (KC / 4); i += 256) {
      int c = i / (KC / 4), g = i - c * (KC / 4);
      int col = n0 + c;
      float4 v = {0.f, 0.f, 0.f, 0.f};
      if (col < 2 * DIM) {
        const float* w = (col < DIM) ? (Wq + (size_t)col * DIM)
                                     : (Wk + (size_t)(col - DIM) * DIM);
        v = *(const float4*)&w[kc + g * 4];
      }
      *(float4*)&ws[c][g * 4] = v;
    }
    __syncthreads();
#pragma unroll 5
    for (int kg = 0; kg < KC / 4; ++kg) {
      float4 xv[4], wv[6];
#pragma unroll
      for (int a = 0; a < 4; ++a) xv[a] = *(const float4*)&xs[ty * 4 + a][kg * 4];
#pragma unroll
      for (int c = 0; c < 6; ++c) wv[c] = *(const float4*)&ws[tx + 16 * c][kg * 4];
#pragma unroll
      for (int a = 0; a < 4; ++a)
#pragma unroll
        for (int c = 0; c < 6; ++c)
          acc[a][c] += wv[c].x * xv[a].x + wv[c].y * xv[a].y +
                       wv[c].z * xv[a].z + wv[c].w * xv[a].w;
    }
  }

#pragma unroll
  for (int cc = 0; cc < 6; ++cc) {
    int col = n0 + tx + 16 * cc;
    if (col < 2 * DIM) {
      float bias; int off;
      if (col < DIM) { bias = bq[col]; off = col + col / DK; }
      else { int c2 = col - DIM; bias = bk[c2]; off = 304 + c2 + c2 / DK; }
#pragma unroll
      for (int a = 0; a < 4; ++a)
        QK[(size_t)(m0 + ty * 4 + a) * QKS + off] = acc[a][cc] + bias;
    }
  }
}

// ---------------------------------------------------------------------------
// K4: attention (unchanged from round 5, passed) — now writes x-rows to xg
// scratch instead of d_out so gcn can tile over columns race-free.
// ---------------------------------------------------------------------------
__global__ __launch_bounds__(256) void attn_kernel(
    const float* __restrict__ QK, const float* __restrict__ X,
    const float* __restrict__ bq, const float* __restrict__ bk,
    const int* __restrict__ slot_src, const int* __restrict__ aa_len,
    float* __restrict__ xout, float* __restrict__ dng, int* __restrict__ mdg) {
  int b = blockIdx.x, tid = threadIdx.x;
  __shared__ __align__(16) float qh[LG][76], kh[LG][76];
  __shared__ float adj[LG][LG + 1];
  __shared__ float coef[4][LG], denomc[4];
  __shared__ int srcs[LG], nlist[LG];
  __shared__ float kthL;
  __shared__ int sh_nneed;

  int length = aa_len[b];
  if (length > LG) length = LG;
  if (tid < LG) srcs[tid] = slot_src[b * LG + tid];
  __syncthreads();

  if (tid < 64) {
    bool isneed = (tid < LG) && (srcs[tid] >= NA);
    unsigned long long nm = __ballot(isneed);
    if (isneed) nlist[__popcll(nm & ((1ull << tid) - 1ull))] = tid;
    if (tid == 0) sh_nneed = __popcll(nm);
  }
  __syncthreads();
  int nneed = sh_nneed;

  if (length <= 1) {
    if (tid < nneed) mdg[srcs[nlist[tid]] - NA] = 0;
    return;
  }

  for (int e = tid; e < LG * LG; e += 256) adj[e / LG][e % LG] = 0.f;

  const float sdk = sqrtf((float)DK);
  int ti = tid >> 3, tj = tid & 7;   // valid for tid < 128
  int i0 = ti * 3, j0 = tj * 6;

  for (int h = 0; h < NH; ++h) {
    for (int i = tid; i < 2 * LG * 19; i += 256) {
      int half = i / (LG * 19);
      int rem = i - half * (LG * 19);
      int r = rem / 19, g = rem - (rem / 19) * 19;
      int src = srcs[r];
      float4 v;
      if (src >= 0) {
        v = *(const float4*)&QK[(size_t)src * QKS + half * 304 + h * 76 + g * 4];
        if (g == 18) v.w = 0.f;
      } else {
        const float* bias = half ? bk : bq;
        int d0 = g * 4;
        v.x = (d0 + 0 < DK) ? bias[h * DK + d0 + 0] : 0.f;
        v.y = (d0 + 1 < DK) ? bias[h * DK + d0 + 1] : 0.f;
        v.z = (d0 + 2 < DK) ? bias[h * DK + d0 + 2] : 0.f;
        v.w = (d0 + 3 < DK) ? bias[h * DK + d0 + 3] : 0.f;
      }
      float* dst = half ? &kh[r][g * 4] : &qh[r][g * 4];
      *(float4*)dst = v;
    }
    __syncthreads();

    if (tid < 128) {
      float acc[3][6];
#pragma unroll
      for (int a = 0; a < 3; ++a)
#pragma unroll
        for (int c = 0; c < 6; ++c) acc[a][c] = 0.f;
      for (int d4 = 0; d4 < 19; ++d4) {
        float4 qv[3], kv[6];
#pragma unroll
        for (int a = 0; a < 3; ++a) qv[a] = *(const float4*)&qh[i0 + a][d4 * 4];
#pragma unroll
        for (int c = 0; c < 6; ++c) kv[c] = *(const float4*)&kh[j0 + c][d4 * 4];
#pragma unroll
        for (int a = 0; a < 3; ++a)
#pragma unroll
          for (int c = 0; c < 6; ++c)
            acc[a][c] += qv[a].x * kv[c].x + qv[a].y * kv[c].y +
                         qv[a].z * kv[c].z + qv[a].w * kv[c].w;
      }
#pragma unroll
      for (int a = 0; a < 3; ++a) {
        float p[6];
#pragma unroll
        for (int c = 0; c < 6; ++c)
          p[c] = (j0 + c < length) ? (acc[a][c] / sdk) : -1e9f;
        float mx = p[0];
#pragma unroll
        for (int c = 1; c < 6; ++c) mx = fmaxf(mx, p[c]);
        mx = fmaxf(mx, __shfl_xor(mx, 1));
        mx = fmaxf(mx, __shfl_xor(mx, 2));
        mx = fmaxf(mx, __shfl_xor(mx, 4));
        float rs = 0.f;
#pragma unroll
        for (int c = 0; c < 6; ++c) { p[c] = expf(p[c] - mx); rs += p[c]; }
        rs += __shfl_xor(rs, 1);
        rs += __shfl_xor(rs, 2);
        rs += __shfl_xor(rs, 4);
        if (i0 + a < length) {
#pragma unroll
          for (int c = 0; c < 6; ++c) adj[i0 + a][j0 + c] += p[c] / rs;
        }
      }
    }
    __syncthreads();
  }

  for (int e = tid; e < LG * LG; e += 256) {
    int i = e / LG, j = e % LG;
    float v = adj[i][j] * 0.25f;
    if (i == j) v = (i < length) ? 1.0f : 0.0f;
    adj[i][j] = v;
  }
  __syncthreads();

  if (tid < 64) {
    unsigned int vb[36];
#pragma unroll
    for (int v = 0; v < 36; ++v) {
      int e = v * 64 + tid;
      vb[v] = __float_as_uint(adj[e / LG][e % LG]);
    }
    unsigned int cur = 0u;
    for (int bit = 30; bit >= 0; --bit) {
      unsigned int cand = cur | (1u << bit);
      int c = 0;
#pragma unroll
      for (int v = 0; v < 36; ++v) c += (vb[v] >= cand) ? 1 : 0;
      c += __shfl_xor(c, 32); c += __shfl_xor(c, 16);
      c += __shfl_xor(c, 8);  c += __shfl_xor(c, 4);
      c += __shfl_xor(c, 2);  c += __shfl_xor(c, 1);
      if (c >= KTOP) cur = cand;
    }
    if (tid == 0) kthL = __uint_as_float(cur);
  }
  __syncthreads();
  const float kth = kthL;

  for (int c0 = 0; c0 < nneed; c0 += 4) {
    int nc = nneed - c0;
    if (nc > 4) nc = 4;
    if (tid < nc * LG) {
      int r = tid / LG, j = tid - (tid / LG) * LG;
      int i = nlist[c0 + r];
      float aij = adj[i][j];
      float v;
      if (j == i) v = aij;
      else {
        float selv = (aij >= kth ? 1.f : 0.f) + (adj[j][i] >= kth ? 1.f : 0.f);
        v = selv * aij;
      }
      coef[r][j] = v;
    }
    __syncthreads();
    if (tid < nc) {
      float sm = 0.f;
      for (int j = 0; j < LG; ++j) sm += coef[tid][j];
      denomc[tid] = sm + 1.f;
    }
    __syncthreads();
    for (int w = tid; w < nc * (DIM / 4); w += 256) {
      int r = w / (DIM / 4), d4 = w - (w / (DIM / 4)) * (DIM / 4);
      float4 acc = {0.f, 0.f, 0.f, 0.f};
      for (int j = 0; j < LG; ++j) {
        int src = srcs[j];
        if (src >= 0) {
          float a = coef[r][j];
          float4 xv = ((const float4*)(X + (size_t)src * DIM))[d4];
          acc.x += a * xv.x; acc.y += a * xv.y;
          acc.z += a * xv.z; acc.w += a * xv.w;
        }
      }
      int n = srcs[nlist[c0 + r]] - NA;
      ((float4*)(xout + (size_t)n * DIM))[d4] = acc;
    }
    if (tid < nc) {
      int n = srcs[nlist[c0 + tid]] - NA;
      mdg[n] = 1;
      dng[n] = denomc[tid];
    }
    __syncthreads();
  }
}

// ---------------------------------------------------------------------------
// K5: gcn as LDS-tiled GEMM. M=2048, N=300, K=300. Tile 32x64, GKC=60,
// micro 2x4 strided cols. fp accumulation: k-ascending groups of 4 with the
// identical 4-term expression -> bitwise-identical to round-5 gcn (passed).
// md=0 rows: clause passthrough in epilogue.
// ---------------------------------------------------------------------------
__global__ __launch_bounds__(256) void gcn_kernel(
    const float* __restrict__ xg, const float* __restrict__ dng,
    const int* __restrict__ mdg, const float* __restrict__ Wg,
    const float* __restrict__ bg, const float* __restrict__ clause,
    float* __restrict__ out) {
  __shared__ __align__(16) float xs[GTM][GKC];
  __shared__ __align__(16) float ws[GTN][GKC];
  int m0 = blockIdx.x * GTM, n0 = blockIdx.y * GTN;
  int tid = threadIdx.x;
  int ty = tid >> 4;   // 0..15 -> rows ty*2+a
  int tx = tid & 15;   // 0..15 -> cols tx+16*cc
  float acc[2][4];
#pragma unroll
  for (int a = 0; a < 2; ++a)
#pragma unroll
    for (int c = 0; c < 4; ++c) acc[a][c] = 0.f;

  for (int kc = 0; kc < DIM; kc += GKC) {
    __syncthreads();
    for (int i = tid; i < GTM * (GKC / 4); i += 256) {
      int r = i / (GKC / 4), g = i - r * (GKC / 4);
      *(float4*)&xs[r][g * 4] =
          *(const float4*)&xg[(size_t)(m0 + r) * DIM + kc + g * 4];
    }
    for (int i = tid; i < GTN * (GKC / 4); i += 256) {
      int c = i / (GKC / 4), g = i - c * (GKC / 4);
      int col = n0 + c;
      float4 v = {0.f, 0.f, 0.f, 0.f};
      if (col < DIM)
        v = *(const float4*)&Wg[(size_t)col * DIM + kc + g * 4];
      *(float4*)&ws[c][g * 4] = v;
    }
    __syncthreads();
#pragma unroll 5
    for (int kg = 0; kg < GKC / 4; ++kg) {
      float4 xv[2], wv[4];
#pragma unroll
      for (int a = 0; a < 2; ++a) xv[a] = *(const float4*)&xs[ty * 2 + a][kg * 4];
#pragma unroll
      for (int c = 0; c < 4; ++c) wv[c] = *(const float4*)&ws[tx + 16 * c][kg * 4];
#pragma unroll
      for (int a = 0; a < 2; ++a)
#pragma unroll
        for (int c = 0; c < 4; ++c)
          acc[a][c] += wv[c].x * xv[a].x + wv[c].y * xv[a].y +
                       wv[c].z * xv[a].z + wv[c].w * xv[a].w;
    }
  }

  int md[2]; float dn[2];
#pragma unroll
  for (int a = 0; a < 2; ++a) {
    int row = m0 + ty * 2 + a;
    md[a] = mdg[row];
    dn[a] = dng[row];
  }
#pragma unroll
  for (int cc = 0; cc < 4; ++cc) {
    int col = n0 + tx + 16 * cc;
    if (col < DIM) {
      float bgc = bg[col];
#pragma unroll
      for (int a = 0; a < 2; ++a) {
        int row = m0 + ty * 2 + a;
        float v;
        if (md[a]) v = fmaxf((acc[a][cc] + bgc) / dn[a], 0.f);
        else v = clause[(size_t)row * DIM + col];
        out[(size_t)row * DIM + col] = v;
      }
    }
  }
}

// ---------------------------------------------------------------------------
extern "C" void kernel_launch(void* const* d_in, const int* in_sizes, int n_in,
                              void* d_out, int out_size, void* d_ws, size_t ws_size,
                              hipStream_t stream) {
  (void)in_sizes; (void)n_in; (void)out_size; (void)ws_size;
  const float* input_embed = (const float*)d_in[0];
  const float* clause      = (const float*)d_in[1];
  const float* aa_mask     = (const float*)d_in[2];
  const int*   aa_len      = (const int*)d_in[3];
  const int*   map_AA      = (const int*)d_in[4];
  const int*   map_AA_idx  = (const int*)d_in[5];
  const int*   map_AS      = (const int*)d_in[6];
  const int*   map_AS_idx  = (const int*)d_in[7];
  const float* Wq = (const float*)d_in[8];
  const float* bq = (const float*)d_in[9];
  const float* Wk = (const float*)d_in[10];
  const float* bk = (const float*)d_in[11];
  const float* Wg = (const float*)d_in[12];
  const float* bg = (const float*)d_in[13];
  float* out = (float*)d_out;

  float* X  = (float*)d_ws;                                  // 4096*300
  float* QK = X + (size_t)(NA + NC) * DIM;                   // 4096*608 (padded)
  int* slot_src = (int*)(QK + (size_t)(NA + NC) * QKS);      // 512*48
  int* acnt = slot_src + B_SZ * LG;                          // 512
  int* alist = acnt + B_SZ;                                  // 512*16 (freed after K1)
  float* dng = (float*)alist;                                // 2048 (aliases alist)
  int* mdg = (int*)(dng + NC);                               // 2048 (aliases alist)
  float* xg = (float*)(alist + B_SZ * ACAP);                 // 2048*300 (after alist)

  hipMemsetAsync(slot_src, 0xFF, (size_t)B_SZ * LG * sizeof(int), stream);
  hipMemsetAsync(acnt, 0x00, (size_t)B_SZ * sizeof(int), stream);
  build_kernel<<<(NA + 255) / 256, 256, 0, stream>>>(map_AA, map_AA_idx,
                                                     slot_src, acnt, alist);
  clause_kernel<<<NC, 128, 0, stream>>>(clause, map_AS, map_AS_idx, X, slot_src);
  aspect_kernel<<<B_SZ, 256, 0, stream>>>(input_embed, aa_mask, acnt, alist, X);
  dim3 qkgrid((NA + NC) / TM, (2 * DIM + TN - 1) / TN);
  qk_kernel<<<qkgrid, 256, 0, stream>>>(X, Wq, bq, Wk, bk, QK);
  attn_kernel<<<B_SZ, 256, 0, stream>>>(QK, X, bq, bk, slot_src, aa_len,
                                        xg, dng, mdg);
  dim3 ggrid(NC / GTM, (DIM + GTN - 1) / GTN);
  gcn_kernel<<<ggrid, 256, 0, stream>>>(xg, dng, mdg, Wg, bg, clause, out);
}

// Round 7
// 178.642 us; speedup vs baseline: 1.7944x; 1.0716x over previous
//
#include <hip/hip_runtime.h>
#include <math.h>

#define B_SZ 512
#define LG 48
#define T_LEN 128
#define DIM 300
#define NA 2048
#define NC 2048
#define NH 4
#define DK 75
#define KTOP 96
#define ACAP 16
#define TM 64
#define TN 96
#define KC 100
#define QKS 608   // padded QK row: 4 heads x 76 (q) + 4 heads x 76 (k)
#define GTM 32
#define GTN 64
#define GKC 60

// ---------------------------------------------------------------------------
// K0: register aspect slots (atomicMax vs -1 init) + per-sentence aspect lists
// ---------------------------------------------------------------------------
__global__ __launch_bounds__(256) void build_kernel(
    const int* __restrict__ mapAA, const int* __restrict__ mapAAi,
    int* __restrict__ slot_src, int* __restrict__ acnt, int* __restrict__ alist) {
  int n = blockIdx.x * 256 + threadIdx.x;
  if (n >= NA) return;
  int b = mapAA[n];
  atomicMax(&slot_src[b * LG + mapAAi[n]], n);
  int pos = atomicAdd(&acnt[b], 1);
  if (pos < ACAP) alist[b * ACAP + pos] = n;
}

// ---------------------------------------------------------------------------
// K1: grouped aspect embedding (unchanged; passed rounds 2-6)
// ---------------------------------------------------------------------------
__global__ __launch_bounds__(256) void aspect_kernel(
    const float* __restrict__ embed, const float* __restrict__ mask,
    const int* __restrict__ acnt, const int* __restrict__ alist,
    float* __restrict__ X) {
  int b = blockIdx.x;
  int na = acnt[b]; if (na > ACAP) na = ACAP;
  if (na == 0) return;
  __shared__ float mLds[ACAP][T_LEN];
  __shared__ float4 eLds[32][DK];
  int tid = threadIdx.x;
  for (int i = tid; i < na * T_LEN; i += 256) {
    int k = i / T_LEN, t = i - k * T_LEN;
    mLds[k][t] = mask[(size_t)alist[b * ACAP + k] * T_LEN + t];
  }
  int nw = na * DK;
  int i0 = tid, i1 = tid + 256;
  int k0 = i0 / DK, d0 = i0 - k0 * DK;
  int k1 = i1 / DK, d1 = i1 - k1 * DK;
  float4 a0 = {0, 0, 0, 0}, a1 = {0, 0, 0, 0};
  const float4* e4 = (const float4*)(embed + (size_t)b * T_LEN * DIM);
  for (int t0 = 0; t0 < T_LEN; t0 += 32) {
    __syncthreads();
    for (int i = tid; i < 32 * DK; i += 256) {
      int t = i / DK, d = i - t * DK;
      eLds[t][d] = e4[(size_t)(t0 + t) * DK + d];
    }
    __syncthreads();
#pragma unroll
    for (int t = 0; t < 32; ++t) {
      if (i0 < nw) {
        float m = mLds[k0][t0 + t]; float4 ev = eLds[t][d0];
        a0.x += m * ev.x; a0.y += m * ev.y; a0.z += m * ev.z; a0.w += m * ev.w;
      }
      if (i1 < nw) {
        float m = mLds[k1][t0 + t]; float4 ev = eLds[t][d1];
        a1.x += m * ev.x; a1.y += m * ev.y; a1.z += m * ev.z; a1.w += m * ev.w;
      }
    }
  }
  if (i0 < nw) ((float4*)(X + (size_t)alist[b * ACAP + k0] * DIM))[d0] = a0;
  if (i1 < nw) ((float4*)(X + (size_t)alist[b * ACAP + k1] * DIM))[d1] = a1;
}

// ---------------------------------------------------------------------------
// K2: clause rows -> X[NA+n]; slot registration (unchanged)
// ---------------------------------------------------------------------------
__global__ __launch_bounds__(128) void clause_kernel(
    const float* __restrict__ clause, const int* __restrict__ mapAS,
    const int* __restrict__ mapASi, float* __restrict__ X,
    int* __restrict__ slot_src) {
  int n = blockIdx.x, t = threadIdx.x;
  const float4* src = (const float4*)(clause + (size_t)n * DIM);
  float4* dst = (float4*)(X + (size_t)(NA + n) * DIM);
  if (t < DIM / 4) dst[t] = src[t];
  if (t == 96) atomicMax(&slot_src[mapAS[n] * LG + mapASi[n]], NA + n);
}

// ---------------------------------------------------------------------------
// K3: QK GEMM. Tile 64x96, KC=100 (reverted — KC=60 regressed ~35us),
// micro 4x6 strided cols (tx+16*cc -> LDS lane-stride 100 == 4 mod 32,
// 2-way = free). k-ascending groups of 4: bitwise-identical across KC.
// ---------------------------------------------------------------------------
__global__ __launch_bounds__(256) void qk_kernel(
    const float* __restrict__ X, const float* __restrict__ Wq,
    const float* __restrict__ bq, const float* __restrict__ Wk,
    const float* __restrict__ bk, float* __restrict__ QK) {
  __shared__ __align__(16) float xs[TM][KC];
  __shared__ __align__(16) float ws[TN][KC];
  int m0 = blockIdx.x * TM, n0 = blockIdx.y * TN;
  int tid = threadIdx.x;
  int ty = tid >> 4;   // 0..15 -> rows ty*4+a
  int tx = tid & 15;   // 0..15 -> cols tx+16*cc
  float acc[4][6];
#pragma unroll
  for (int a = 0; a < 4; ++a)
#pragma unroll
    for (int c = 0; c < 6; ++c) acc[a][c] = 0.f;

  for (int kc = 0; kc < DIM; kc += KC) {
    __syncthreads();
    for (int i = tid; i < TM * (KC / 4); i += 256) {
      int r = i / (KC / 4), g = i - r * (KC / 4);
      *(float4*)&xs[r][g * 4] =
          *(const float4*)&X[(size_t)(m0 + r) * DIM + kc + g * 4];
    }
    for (int i = tid; i < TN * (KC / 4); i += 256) {
      int c = i / (KC / 4), g = i - c * (KC / 4);
      int col = n0 + c;
      float4 v = {0.f, 0.f, 0.f, 0.f};
      if (col < 2 * DIM) {
        const float* w = (col < DIM) ? (Wq + (size_t)col * DIM)
                                     : (Wk + (size_t)(col - DIM) * DIM);
        v = *(const float4*)&w[kc + g * 4];
      }
      *(float4*)&ws[c][g * 4] = v;
    }
    __syncthreads();
#pragma unroll 5
    for (int kg = 0; kg < KC / 4; ++kg) {
      float4 xv[4], wv[6];
#pragma unroll
      for (int a = 0; a < 4; ++a) xv[a] = *(const float4*)&xs[ty * 4 + a][kg * 4];
#pragma unroll
      for (int c = 0; c < 6; ++c) wv[c] = *(const float4*)&ws[tx + 16 * c][kg * 4];
#pragma unroll
      for (int a = 0; a < 4; ++a)
#pragma unroll
        for (int c = 0; c < 6; ++c)
          acc[a][c] += wv[c].x * xv[a].x + wv[c].y * xv[a].y +
                       wv[c].z * xv[a].z + wv[c].w * xv[a].w;
    }
  }

#pragma unroll
  for (int cc = 0; cc < 6; ++cc) {
    int col = n0 + tx + 16 * cc;
    if (col < 2 * DIM) {
      float bias; int off;
      if (col < DIM) { bias = bq[col]; off = col + col / DK; }
      else { int c2 = col - DIM; bias = bk[c2]; off = 304 + c2 + c2 / DK; }
#pragma unroll
      for (int a = 0; a < 4; ++a)
        QK[(size_t)(m0 + ty * 4 + a) * QKS + off] = acc[a][cc] + bias;
    }
  }
}

// ---------------------------------------------------------------------------
// K4a: per-(batch,head) scores + softmax -> adjh[b][h][48][48].
// Identical fp expression graph / lane mapping / shfl order as the merged
// round-6 attn (passed); heads now parallel across blocks (2048 blocks).
// ---------------------------------------------------------------------------
__global__ __launch_bounds__(128) void score_kernel(
    const float* __restrict__ QK, const float* __restrict__ bq,
    const float* __restrict__ bk, const int* __restrict__ slot_src,
    const int* __restrict__ aa_len, float* __restrict__ adjh) {
  int b = blockIdx.x, h = blockIdx.y, tid = threadIdx.x;
  int length = aa_len[b];
  if (length > LG) length = LG;
  if (length <= 1) return;   // topk_kernel handles passthrough; adjh unread

  __shared__ __align__(16) float qh[LG][76], kh[LG][76];
  __shared__ int srcs[LG];
  if (tid < LG) srcs[tid] = slot_src[b * LG + tid];
  __syncthreads();

  for (int i = tid; i < 2 * LG * 19; i += 128) {
    int half = i / (LG * 19);
    int rem = i - half * (LG * 19);
    int r = rem / 19, g = rem - (rem / 19) * 19;
    int src = srcs[r];
    float4 v;
    if (src >= 0) {
      v = *(const float4*)&QK[(size_t)src * QKS + half * 304 + h * 76 + g * 4];
      if (g == 18) v.w = 0.f;
    } else {
      const float* bias = half ? bk : bq;
      int d0 = g * 4;
      v.x = (d0 + 0 < DK) ? bias[h * DK + d0 + 0] : 0.f;
      v.y = (d0 + 1 < DK) ? bias[h * DK + d0 + 1] : 0.f;
      v.z = (d0 + 2 < DK) ? bias[h * DK + d0 + 2] : 0.f;
      v.w = (d0 + 3 < DK) ? bias[h * DK + d0 + 3] : 0.f;
    }
    float* dst = half ? &kh[r][g * 4] : &qh[r][g * 4];
    *(float4*)dst = v;
  }
  __syncthreads();

  const float sdk = sqrtf((float)DK);
  int ti = tid >> 3, tj = tid & 7;
  int i0 = ti * 3, j0 = tj * 6;
  float acc[3][6];
#pragma unroll
  for (int a = 0; a < 3; ++a)
#pragma unroll
    for (int c = 0; c < 6; ++c) acc[a][c] = 0.f;
  for (int d4 = 0; d4 < 19; ++d4) {
    float4 qv[3], kv[6];
#pragma unroll
    for (int a = 0; a < 3; ++a) qv[a] = *(const float4*)&qh[i0 + a][d4 * 4];
#pragma unroll
    for (int c = 0; c < 6; ++c) kv[c] = *(const float4*)&kh[j0 + c][d4 * 4];
#pragma unroll
    for (int a = 0; a < 3; ++a)
#pragma unroll
      for (int c = 0; c < 6; ++c)
        acc[a][c] += qv[a].x * kv[c].x + qv[a].y * kv[c].y +
                     qv[a].z * kv[c].z + qv[a].w * kv[c].w;
  }
  float* outp = adjh + ((size_t)(b * NH + h)) * (LG * LG);
#pragma unroll
  for (int a = 0; a < 3; ++a) {
    float p[6];
#pragma unroll
    for (int c = 0; c < 6; ++c)
      p[c] = (j0 + c < length) ? (acc[a][c] / sdk) : -1e9f;
    float mx = p[0];
#pragma unroll
    for (int c = 1; c < 6; ++c) mx = fmaxf(mx, p[c]);
    mx = fmaxf(mx, __shfl_xor(mx, 1));
    mx = fmaxf(mx, __shfl_xor(mx, 2));
    mx = fmaxf(mx, __shfl_xor(mx, 4));
    float rs = 0.f;
#pragma unroll
    for (int c = 0; c < 6; ++c) { p[c] = expf(p[c] - mx); rs += p[c]; }
    rs += __shfl_xor(rs, 1);
    rs += __shfl_xor(rs, 2);
    rs += __shfl_xor(rs, 4);
    if (i0 + a < length) {
#pragma unroll
      for (int c = 0; c < 6; ++c)
        outp[(i0 + a) * LG + j0 + c] = p[c] / rs;
    }
  }
}

// ---------------------------------------------------------------------------
// K4b: head-mean (ascending h — exact merged order), diag/mask, block-wide
// binary-search top-k (round-3 proven), coef/denom/xout epilogue (unchanged).
// ---------------------------------------------------------------------------
__global__ __launch_bounds__(256) void topk_kernel(
    const float* __restrict__ adjh, const float* __restrict__ X,
    const int* __restrict__ slot_src, const int* __restrict__ aa_len,
    float* __restrict__ xout, float* __restrict__ dng, int* __restrict__ mdg) {
  int b = blockIdx.x, tid = threadIdx.x;
  __shared__ float adj[LG][LG + 1];
  __shared__ float coef[4][LG], denomc[4];
  __shared__ int srcs[LG], nlist[LG];
  __shared__ int wsum4[4];
  __shared__ int sh_nneed;

  int length = aa_len[b];
  if (length > LG) length = LG;
  if (tid < LG) srcs[tid] = slot_src[b * LG + tid];
  __syncthreads();

  if (tid < 64) {
    bool isneed = (tid < LG) && (srcs[tid] >= NA);
    unsigned long long nm = __ballot(isneed);
    if (isneed) nlist[__popcll(nm & ((1ull << tid) - 1ull))] = tid;
    if (tid == 0) sh_nneed = __popcll(nm);
  }
  __syncthreads();
  int nneed = sh_nneed;

  if (length <= 1) {
    if (tid < nneed) mdg[srcs[nlist[tid]] - NA] = 0;
    return;
  }

  const float* base = adjh + (size_t)b * NH * (LG * LG);
  for (int e = tid; e < LG * LG; e += 256) {
    int i = e / LG, j = e - (e / LG) * LG;
    float v = 0.f;
    if (i < length) {
      for (int h = 0; h < NH; ++h) v += base[h * (LG * LG) + e];
      v *= 0.25f;
    }
    if (i == j) v = (i < length) ? 1.0f : 0.0f;
    adj[i][j] = v;
  }
  __syncthreads();

  unsigned int vb[9];
#pragma unroll
  for (int v = 0; v < 9; ++v) {
    int e = v * 256 + tid;
    vb[v] = __float_as_uint(adj[e / LG][e % LG]);
  }
  unsigned int cur = 0u;
  int lid = tid & 63, wid = tid >> 6;
  for (int bit = 30; bit >= 0; --bit) {
    unsigned int cand = cur | (1u << bit);
    int c = 0;
#pragma unroll
    for (int v = 0; v < 9; ++v) c += (vb[v] >= cand) ? 1 : 0;
    c += __shfl_xor(c, 32); c += __shfl_xor(c, 16);
    c += __shfl_xor(c, 8);  c += __shfl_xor(c, 4);
    c += __shfl_xor(c, 2);  c += __shfl_xor(c, 1);
    if (lid == 0) wsum4[wid] = c;
    __syncthreads();
    int tot = wsum4[0] + wsum4[1] + wsum4[2] + wsum4[3];
    if (tot >= KTOP) cur = cand;
    __syncthreads();
  }
  const float kth = __uint_as_float(cur);

  for (int c0 = 0; c0 < nneed; c0 += 4) {
    int nc = nneed - c0;
    if (nc > 4) nc = 4;
    if (tid < nc * LG) {
      int r = tid / LG, j = tid - (tid / LG) * LG;
      int i = nlist[c0 + r];
      float aij = adj[i][j];
      float v;
      if (j == i) v = aij;
      else {
        float selv = (aij >= kth ? 1.f : 0.f) + (adj[j][i] >= kth ? 1.f : 0.f);
        v = selv * aij;
      }
      coef[r][j] = v;
    }
    __syncthreads();
    if (tid < nc) {
      float sm = 0.f;
      for (int j = 0; j < LG; ++j) sm += coef[tid][j];
      denomc[tid] = sm + 1.f;
    }
    __syncthreads();
    for (int w = tid; w < nc * (DIM / 4); w += 256) {
      int r = w / (DIM / 4), d4 = w - (w / (DIM / 4)) * (DIM / 4);
      float4 acc = {0.f, 0.f, 0.f, 0.f};
      for (int j = 0; j < LG; ++j) {
        int src = srcs[j];
        if (src >= 0) {
          float a = coef[r][j];
          float4 xv = ((const float4*)(X + (size_t)src * DIM))[d4];
          acc.x += a * xv.x; acc.y += a * xv.y;
          acc.z += a * xv.z; acc.w += a * xv.w;
        }
      }
      int n = srcs[nlist[c0 + r]] - NA;
      ((float4*)(xout + (size_t)n * DIM))[d4] = acc;
    }
    if (tid < nc) {
      int n = srcs[nlist[c0 + tid]] - NA;
      mdg[n] = 1;
      dng[n] = denomc[tid];
    }
    __syncthreads();
  }
}

// ---------------------------------------------------------------------------
// K5: gcn GEMM (unchanged from round 6, passed)
// ---------------------------------------------------------------------------
__global__ __launch_bounds__(256) void gcn_kernel(
    const float* __restrict__ xg, const float* __restrict__ dng,
    const int* __restrict__ mdg, const float* __restrict__ Wg,
    const float* __restrict__ bg, const float* __restrict__ clause,
    float* __restrict__ out) {
  __shared__ __align__(16) float xs[GTM][GKC];
  __shared__ __align__(16) float ws[GTN][GKC];
  int m0 = blockIdx.x * GTM, n0 = blockIdx.y * GTN;
  int tid = threadIdx.x;
  int ty = tid >> 4;
  int tx = tid & 15;
  float acc[2][4];
#pragma unroll
  for (int a = 0; a < 2; ++a)
#pragma unroll
    for (int c = 0; c < 4; ++c) acc[a][c] = 0.f;

  for (int kc = 0; kc < DIM; kc += GKC) {
    __syncthreads();
    for (int i = tid; i < GTM * (GKC / 4); i += 256) {
      int r = i / (GKC / 4), g = i - r * (GKC / 4);
      *(float4*)&xs[r][g * 4] =
          *(const float4*)&xg[(size_t)(m0 + r) * DIM + kc + g * 4];
    }
    for (int i = tid; i < GTN * (GKC / 4); i += 256) {
      int c = i / (GKC / 4), g = i - c * (GKC / 4);
      int col = n0 + c;
      float4 v = {0.f, 0.f, 0.f, 0.f};
      if (col < DIM)
        v = *(const float4*)&Wg[(size_t)col * DIM + kc + g * 4];
      *(float4*)&ws[c][g * 4] = v;
    }
    __syncthreads();
#pragma unroll 5
    for (int kg = 0; kg < GKC / 4; ++kg) {
      float4 xv[2], wv[4];
#pragma unroll
      for (int a = 0; a < 2; ++a) xv[a] = *(const float4*)&xs[ty * 2 + a][kg * 4];
#pragma unroll
      for (int c = 0; c < 4; ++c) wv[c] = *(const float4*)&ws[tx + 16 * c][kg * 4];
#pragma unroll
      for (int a = 0; a < 2; ++a)
#pragma unroll
        for (int c = 0; c < 4; ++c)
          acc[a][c] += wv[c].x * xv[a].x + wv[c].y * xv[a].y +
                       wv[c].z * xv[a].z + wv[c].w * xv[a].w;
    }
  }

  int md[2]; float dn[2];
#pragma unroll
  for (int a = 0; a < 2; ++a) {
    int row = m0 + ty * 2 + a;
    md[a] = mdg[row];
    dn[a] = dng[row];
  }
#pragma unroll
  for (int cc = 0; cc < 4; ++cc) {
    int col = n0 + tx + 16 * cc;
    if (col < DIM) {
      float bgc = bg[col];
#pragma unroll
      for (int a = 0; a < 2; ++a) {
        int row = m0 + ty * 2 + a;
        float v;
        if (md[a]) v = fmaxf((acc[a][cc] + bgc) / dn[a], 0.f);
        else v = clause[(size_t)row * DIM + col];
        out[(size_t)row * DIM + col] = v;
      }
    }
  }
}

// ---------------------------------------------------------------------------
extern "C" void kernel_launch(void* const* d_in, const int* in_sizes, int n_in,
                              void* d_out, int out_size, void* d_ws, size_t ws_size,
                              hipStream_t stream) {
  (void)in_sizes; (void)n_in; (void)out_size; (void)ws_size;
  const float* input_embed = (const float*)d_in[0];
  const float* clause      = (const float*)d_in[1];
  const float* aa_mask     = (const float*)d_in[2];
  const int*   aa_len      = (const int*)d_in[3];
  const int*   map_AA      = (const int*)d_in[4];
  const int*   map_AA_idx  = (const int*)d_in[5];
  const int*   map_AS      = (const int*)d_in[6];
  const int*   map_AS_idx  = (const int*)d_in[7];
  const float* Wq = (const float*)d_in[8];
  const float* bq = (const float*)d_in[9];
  const float* Wk = (const float*)d_in[10];
  const float* bk = (const float*)d_in[11];
  const float* Wg = (const float*)d_in[12];
  const float* bg = (const float*)d_in[13];
  float* out = (float*)d_out;

  float* X  = (float*)d_ws;                                  // 4096*300
  float* QK = X + (size_t)(NA + NC) * DIM;                   // 4096*608
  int* slot_src = (int*)(QK + (size_t)(NA + NC) * QKS);      // 512*48
  int* acnt = slot_src + B_SZ * LG;                          // 512
  int* alist = acnt + B_SZ;                                  // 512*16
  float* dng = (float*)alist;                                // 2048 (aliases alist)
  int* mdg = (int*)(dng + NC);                               // 2048 (aliases alist)
  float* xg = (float*)(alist + B_SZ * ACAP);                 // 2048*300
  float* adjh = xg + (size_t)NC * DIM;                       // 512*4*2304 (18.9MB)

  hipMemsetAsync(slot_src, 0xFF, (size_t)B_SZ * LG * sizeof(int), stream);
  hipMemsetAsync(acnt, 0x00, (size_t)B_SZ * sizeof(int), stream);
  build_kernel<<<(NA + 255) / 256, 256, 0, stream>>>(map_AA, map_AA_idx,
                                                     slot_src, acnt, alist);
  clause_kernel<<<NC, 128, 0, stream>>>(clause, map_AS, map_AS_idx, X, slot_src);
  aspect_kernel<<<B_SZ, 256, 0, stream>>>(input_embed, aa_mask, acnt, alist, X);
  dim3 qkgrid((NA + NC) / TM, (2 * DIM + TN - 1) / TN);
  qk_kernel<<<qkgrid, 256, 0, stream>>>(X, Wq, bq, Wk, bk, QK);
  dim3 sgrid(B_SZ, NH);
  score_kernel<<<sgrid, 128, 0, stream>>>(QK, bq, bk, slot_src, aa_len, adjh);
  topk_kernel<<<B_SZ, 256, 0, stream>>>(adjh, X, slot_src, aa_len, xg, dng, mdg);
  dim3 ggrid(NC / GTM, (DIM + GTN - 1) / GTN);
  gcn_kernel<<<ggrid, 256, 0, stream>>>(xg, dng, mdg, Wg, bg, clause, out);
}